// Round 2
// baseline (1138.931 us; speedup 1.0000x reference)
//
#include <hip/hip_runtime.h>
#include <hip/hip_bf16.h>

// Problem sizes (fixed): B=8, T=2048, H=64, M=32, S=20, E=3, IN=32
#define Bv  8
#define Tv  2048
#define Hv  64
#define Mv  32
#define Sv  20
#define Ev  3
#define INv 32
#define LOG2E 1.44269504088896340736f

// ---------------------------------------------------------------------------
// Kernel 1: memories[b,t,:] = softmax((x@IQ) @ mem^T) @ mem        [B*T, 32]
// ---------------------------------------------------------------------------
__global__ __launch_bounds__(256) void mem_kernel(
    const float* __restrict__ x,        // [B*T, 32]
    const float* __restrict__ memory,   // [20, 32]
    const float* __restrict__ iq,       // [32, 32]
    float* __restrict__ memout)         // [B*T, 32]
{
    __shared__ float sIQ[32][32];
    __shared__ float sM[20][32];
    int tid = threadIdx.x;
    for (int i = tid; i < 32 * 32; i += 256) sIQ[i >> 5][i & 31] = iq[i];
    for (int i = tid; i < 20 * 32; i += 256) sM[i >> 5][i & 31] = memory[i];
    __syncthreads();

    int t = blockIdx.x * 256 + tid;     // token index < B*T
    const float4* xr = (const float4*)(x + (size_t)t * INv);
    float xv[32];
#pragma unroll
    for (int i = 0; i < 8; ++i) {
        float4 v = xr[i];
        xv[4*i] = v.x; xv[4*i+1] = v.y; xv[4*i+2] = v.z; xv[4*i+3] = v.w;
    }
    float qm[32];
#pragma unroll
    for (int m = 0; m < 32; ++m) qm[m] = 0.f;
    for (int i = 0; i < 32; ++i) {
        float xi = xv[i];
#pragma unroll
        for (int m4 = 0; m4 < 8; ++m4) {
            float4 wv = *(const float4*)&sIQ[i][m4 * 4];
            qm[4*m4]   = fmaf(xi, wv.x, qm[4*m4]);
            qm[4*m4+1] = fmaf(xi, wv.y, qm[4*m4+1]);
            qm[4*m4+2] = fmaf(xi, wv.z, qm[4*m4+2]);
            qm[4*m4+3] = fmaf(xi, wv.w, qm[4*m4+3]);
        }
    }
    float sc[20];
#pragma unroll
    for (int j = 0; j < 20; ++j) {
        float acc = 0.f;
#pragma unroll
        for (int m = 0; m < 32; ++m) acc = fmaf(qm[m], sM[j][m], acc);
        sc[j] = acc;
    }
    float mx = sc[0];
#pragma unroll
    for (int j = 1; j < 20; ++j) mx = fmaxf(mx, sc[j]);
    float psum = 0.f, p[20];
#pragma unroll
    for (int j = 0; j < 20; ++j) { p[j] = exp2f((sc[j] - mx) * LOG2E); psum += p[j]; }
    float inv = 1.0f / psum;
    float mo[32];
#pragma unroll
    for (int m = 0; m < 32; ++m) mo[m] = 0.f;
    for (int j = 0; j < 20; ++j) {
        float pj = p[j];
#pragma unroll
        for (int m = 0; m < 32; ++m) mo[m] = fmaf(pj, sM[j][m], mo[m]);
    }
    float4* outp = (float4*)(memout + (size_t)t * Mv);
#pragma unroll
    for (int m4 = 0; m4 < 8; ++m4) {
        float4 v;
        v.x = mo[4*m4] * inv; v.y = mo[4*m4+1] * inv;
        v.z = mo[4*m4+2] * inv; v.w = mo[4*m4+3] * inv;
        outp[m4] = v;
    }
}

// ---------------------------------------------------------------------------
// Kernel 2: QKV projection. Per block: one (e,b) and a 64-row t-tile.
// Output tile 64 x 96 ([Q|K|V]); 256 threads, 4x6 register blocking.
// ---------------------------------------------------------------------------
__global__ __launch_bounds__(256) void qkv_kernel(
    const float* __restrict__ hidden,   // [E,B,T,H]
    const float* __restrict__ Wq,       // [E,H,M]
    const float* __restrict__ Wk,
    const float* __restrict__ Wv,
    float* __restrict__ Qo,             // [E,B,T,M]
    float* __restrict__ Ko,
    float* __restrict__ Vo)
{
    __shared__ float sHT[64][68];       // hidden tile transposed [h][t], pad 68
    __shared__ float sW[64][100];       // [h][ Wq(0..31) | Wk(32..63) | Wv(64..95) ]
    int bid  = blockIdx.x;              // 768 = E*B*32
    int tile = bid & 31;
    int b    = (bid >> 5) & 7;
    int e    = bid >> 8;
    int tid  = threadIdx.x;
    size_t row0 = ((size_t)(e * Bv + b)) * Tv + (size_t)tile * 64;
    const float* hbase = hidden + row0 * Hv;

    {   // load + transpose hidden 64x64
        int r  = tid >> 2;
        int c4 = tid & 3;
#pragma unroll
        for (int hh = 0; hh < 4; ++hh) {
            int h4 = c4 + hh * 4;       // float4 index 0..15
            float4 v = ((const float4*)(hbase + (size_t)r * Hv))[h4];
            sHT[h4*4+0][r] = v.x; sHT[h4*4+1][r] = v.y;
            sHT[h4*4+2][r] = v.z; sHT[h4*4+3][r] = v.w;
        }
    }
    {   // load W for this expert
        const float* wq = Wq + (size_t)e * Hv * Mv;
        const float* wk = Wk + (size_t)e * Hv * Mv;
        const float* wv = Wv + (size_t)e * Hv * Mv;
        for (int i = tid; i < Hv * Mv; i += 256) {
            int h = i >> 5, m = i & 31;
            sW[h][m]      = wq[i];
            sW[h][32 + m] = wk[i];
            sW[h][64 + m] = wv[i];
        }
    }
    __syncthreads();

    int ty = tid >> 4, tx = tid & 15;
    float acc[4][6];
#pragma unroll
    for (int i = 0; i < 4; ++i)
#pragma unroll
        for (int j = 0; j < 6; ++j) acc[i][j] = 0.f;

    for (int h = 0; h < 64; ++h) {
        float4 av = *(const float4*)&sHT[h][ty * 4];
        float a[4] = {av.x, av.y, av.z, av.w};
        float bb[6];
#pragma unroll
        for (int j = 0; j < 6; ++j) bb[j] = sW[h][tx * 6 + j];
#pragma unroll
        for (int i = 0; i < 4; ++i)
#pragma unroll
            for (int j = 0; j < 6; ++j) acc[i][j] = fmaf(a[i], bb[j], acc[i][j]);
    }
#pragma unroll
    for (int i = 0; i < 4; ++i) {
        size_t row = row0 + (size_t)(ty * 4 + i);
#pragma unroll
        for (int j = 0; j < 6; ++j) {
            int c = tx * 6 + j;
            float v = acc[i][j];
            if (c < 32)      Qo[row * Mv + c]        = v;
            else if (c < 64) Ko[row * Mv + (c - 32)] = v;
            else             Vo[row * Mv + (c - 64)] = v;
        }
    }
}

// ---------------------------------------------------------------------------
// Kernel 3: flash attention + cosine epilogue.
// Block = 4 waves over the SAME 64 q rows; wave w handles k in [w*512,(w+1)*512).
// One q row per lane; K/V rows are wave-uniform loads (broadcast, no LDS in loop).
// Partials (m, l, O[32]) combined via LDS; wave 0 finalizes + cosine + fp32 store.
// ---------------------------------------------------------------------------
__global__ __launch_bounds__(256, 3) void attn_kernel(
    const float* __restrict__ Qp,       // [E,B,T,M]
    const float* __restrict__ Kp,
    const float* __restrict__ Vp,
    const float* __restrict__ memv,     // [B*T, M]
    float* __restrict__ out)            // [B,T,E] fp32
{
    __shared__ float red[4][64][34];    // [wave][row][ m, l, O[32] ]
    int bid  = blockIdx.x;              // 768
    int tile = bid & 31;
    int b    = (bid >> 5) & 7;
    int e    = bid >> 8;
    int tid  = threadIdx.x;
    int lane = tid & 63;
    int w    = tid >> 6;
    int t    = tile * 64 + lane;
    size_t eb = (size_t)(e * Bv + b);

    const float4* qr = (const float4*)(Qp + (eb * Tv + t) * Mv);
    float q[32];
#pragma unroll
    for (int i = 0; i < 8; ++i) {
        float4 v = qr[i];
        q[4*i] = v.x; q[4*i+1] = v.y; q[4*i+2] = v.z; q[4*i+3] = v.w;
    }
    float O[32];
#pragma unroll
    for (int i = 0; i < 32; ++i) O[i] = 0.f;
    float mI = -3.0e38f, l = 0.f;

    const float* Kb = Kp + eb * Tv * Mv;
    const float* Vb = Vp + eb * Tv * Mv;
    const int k0 = w * 512;

    for (int kc = 0; kc < 512; kc += 16) {
        const float* kch = Kb + (size_t)(k0 + kc) * Mv;
        float s[16];
#pragma unroll
        for (int kk = 0; kk < 16; ++kk) {
            const float4* kr = (const float4*)(kch + kk * Mv);
            float4 k0v = kr[0], k1v = kr[1], k2v = kr[2], k3v = kr[3];
            float4 k4v = kr[4], k5v = kr[5], k6v = kr[6], k7v = kr[7];
            float a0 = q[0]*k0v.x + q[1]*k0v.y + q[2]*k0v.z + q[3]*k0v.w;
            float a1 = q[4]*k1v.x + q[5]*k1v.y + q[6]*k1v.z + q[7]*k1v.w;
            float a2 = q[8]*k2v.x + q[9]*k2v.y + q[10]*k2v.z + q[11]*k2v.w;
            float a3 = q[12]*k3v.x + q[13]*k3v.y + q[14]*k3v.z + q[15]*k3v.w;
            float a4 = q[16]*k4v.x + q[17]*k4v.y + q[18]*k4v.z + q[19]*k4v.w;
            float a5 = q[20]*k5v.x + q[21]*k5v.y + q[22]*k5v.z + q[23]*k5v.w;
            float a6 = q[24]*k6v.x + q[25]*k6v.y + q[26]*k6v.z + q[27]*k6v.w;
            float a7 = q[28]*k7v.x + q[29]*k7v.y + q[30]*k7v.z + q[31]*k7v.w;
            s[kk] = ((a0 + a1) + (a2 + a3)) + ((a4 + a5) + (a6 + a7));
        }
        float cm = s[0];
#pragma unroll
        for (int kk = 1; kk < 16; ++kk) cm = fmaxf(cm, s[kk]);
        float mNew  = fmaxf(mI, cm);
        float alpha = exp2f((mI - mNew) * LOG2E);
        l *= alpha;
#pragma unroll
        for (int i = 0; i < 32; ++i) O[i] *= alpha;
        mI = mNew;

        const float* vch = Vb + (size_t)(k0 + kc) * Mv;
#pragma unroll
        for (int kk = 0; kk < 16; ++kk) {
            float p = exp2f((s[kk] - mNew) * LOG2E);
            l += p;
            const float4* vr = (const float4*)(vch + kk * Mv);
#pragma unroll
            for (int i = 0; i < 8; ++i) {
                float4 v = vr[i];
                O[4*i]   = fmaf(p, v.x, O[4*i]);
                O[4*i+1] = fmaf(p, v.y, O[4*i+1]);
                O[4*i+2] = fmaf(p, v.z, O[4*i+2]);
                O[4*i+3] = fmaf(p, v.w, O[4*i+3]);
            }
        }
    }

    // write per-wave partials
    red[w][lane][0] = mI;
    red[w][lane][1] = l;
#pragma unroll
    for (int i = 0; i < 32; ++i) red[w][lane][2 + i] = O[i];
    __syncthreads();

    if (w == 0) {
        float M = red[0][lane][0];
#pragma unroll
        for (int ww = 1; ww < 4; ++ww) M = fmaxf(M, red[ww][lane][0]);
        float L = 0.f;
        float Of[32];
#pragma unroll
        for (int i = 0; i < 32; ++i) Of[i] = 0.f;
#pragma unroll
        for (int ww = 0; ww < 4; ++ww) {
            float a  = exp2f((red[ww][lane][0] - M) * LOG2E);
            L += red[ww][lane][1] * a;
#pragma unroll
            for (int i = 0; i < 32; ++i)
                Of[i] = fmaf(a, red[ww][lane][2 + i], Of[i]);
        }
        // cosine with memories; out_vec = Of / L
        const float4* mr = (const float4*)(memv + ((size_t)b * Tv + t) * Mv);
        float dot = 0.f, nm = 0.f, no = 0.f;
#pragma unroll
        for (int i = 0; i < 8; ++i) {
            float4 mv = mr[i];
            float m0 = mv.x, m1 = mv.y, m2 = mv.z, m3 = mv.w;
            dot = fmaf(m0, Of[4*i], dot);   dot = fmaf(m1, Of[4*i+1], dot);
            dot = fmaf(m2, Of[4*i+2], dot); dot = fmaf(m3, Of[4*i+3], dot);
            nm  = fmaf(m0, m0, nm); nm = fmaf(m1, m1, nm);
            nm  = fmaf(m2, m2, nm); nm = fmaf(m3, m3, nm);
            no  = fmaf(Of[4*i], Of[4*i], no);     no = fmaf(Of[4*i+1], Of[4*i+1], no);
            no  = fmaf(Of[4*i+2], Of[4*i+2], no); no = fmaf(Of[4*i+3], Of[4*i+3], no);
        }
        float na = fmaxf(sqrtf(nm), 1e-8f);
        float nb = fmaxf(sqrtf(no) / L, 1e-8f);
        float cosv = (dot / L) / (na * nb);
        out[((size_t)b * Tv + t) * Ev + e] = cosv;   // fp32 store (ref output is float32)
    }
}

// ---------------------------------------------------------------------------
extern "C" void kernel_launch(void* const* d_in, const int* in_sizes, int n_in,
                              void* d_out, int out_size, void* d_ws, size_t ws_size,
                              hipStream_t stream) {
    const float* x      = (const float*)d_in[0];   // [B,T,IN]
    const float* hidden = (const float*)d_in[1];   // [E,B,T,H]
    const float* memory = (const float*)d_in[2];   // [S,M]
    const float* Wq     = (const float*)d_in[3];   // [E,H,M]
    const float* Wk     = (const float*)d_in[4];
    const float* Wv     = (const float*)d_in[5];
    const float* iq     = (const float*)d_in[6];   // [IN,M]
    float* out          = (float*)d_out;           // [B,T,E] fp32

    float* ws = (float*)d_ws;
    // workspace layout (floats): memories | Q | K | V  (total 20 MiB)
    const size_t MEMO = 0;
    const size_t QO   = MEMO + (size_t)Bv * Tv * Mv;          //   524288
    const size_t KO   = QO + (size_t)Ev * Bv * Tv * Mv;       // + 1572864
    const size_t VO   = KO + (size_t)Ev * Bv * Tv * Mv;
    float* memout = ws + MEMO;
    float* Qb = ws + QO;
    float* Kb = ws + KO;
    float* Vb = ws + VO;

    mem_kernel<<<(Bv * Tv) / 256, 256, 0, stream>>>(x, memory, iq, memout);
    qkv_kernel<<<Ev * Bv * (Tv / 64), 256, 0, stream>>>(hidden, Wq, Wk, Wv, Qb, Kb, Vb);
    attn_kernel<<<Ev * Bv * (Tv / 64), 256, 0, stream>>>(Qb, Kb, Vb, memout, out);
}

// Round 3
// 891.155 us; speedup vs baseline: 1.2780x; 1.2780x over previous
//
#include <hip/hip_runtime.h>
#include <hip/hip_bf16.h>

// Problem sizes (fixed): B=8, T=2048, H=64, M=32, S=20, E=3, IN=32
#define Bv  8
#define Tv  2048
#define Hv  64
#define Mv  32
#define Sv  20
#define Ev  3
#define INv 32
#define LOG2E 1.44269504088896340736f

// ---------------------------------------------------------------------------
// Kernel 1: memories[b,t,:] = softmax((x@IQ) @ mem^T) @ mem        [B*T, 32]
// ---------------------------------------------------------------------------
__global__ __launch_bounds__(256) void mem_kernel(
    const float* __restrict__ x,        // [B*T, 32]
    const float* __restrict__ memory,   // [20, 32]
    const float* __restrict__ iq,       // [32, 32]
    float* __restrict__ memout)         // [B*T, 32]
{
    __shared__ float sIQ[32][32];
    __shared__ float sM[20][32];
    int tid = threadIdx.x;
    for (int i = tid; i < 32 * 32; i += 256) sIQ[i >> 5][i & 31] = iq[i];
    for (int i = tid; i < 20 * 32; i += 256) sM[i >> 5][i & 31] = memory[i];
    __syncthreads();

    int t = blockIdx.x * 256 + tid;     // token index < B*T
    const float4* xr = (const float4*)(x + (size_t)t * INv);
    float xv[32];
#pragma unroll
    for (int i = 0; i < 8; ++i) {
        float4 v = xr[i];
        xv[4*i] = v.x; xv[4*i+1] = v.y; xv[4*i+2] = v.z; xv[4*i+3] = v.w;
    }
    float qm[32];
#pragma unroll
    for (int m = 0; m < 32; ++m) qm[m] = 0.f;
    for (int i = 0; i < 32; ++i) {
        float xi = xv[i];
#pragma unroll
        for (int m4 = 0; m4 < 8; ++m4) {
            float4 wv = *(const float4*)&sIQ[i][m4 * 4];
            qm[4*m4]   = fmaf(xi, wv.x, qm[4*m4]);
            qm[4*m4+1] = fmaf(xi, wv.y, qm[4*m4+1]);
            qm[4*m4+2] = fmaf(xi, wv.z, qm[4*m4+2]);
            qm[4*m4+3] = fmaf(xi, wv.w, qm[4*m4+3]);
        }
    }
    float sc[20];
#pragma unroll
    for (int j = 0; j < 20; ++j) {
        float acc = 0.f;
#pragma unroll
        for (int m = 0; m < 32; ++m) acc = fmaf(qm[m], sM[j][m], acc);
        sc[j] = acc;
    }
    float mx = sc[0];
#pragma unroll
    for (int j = 1; j < 20; ++j) mx = fmaxf(mx, sc[j]);
    float psum = 0.f, p[20];
#pragma unroll
    for (int j = 0; j < 20; ++j) { p[j] = exp2f((sc[j] - mx) * LOG2E); psum += p[j]; }
    float inv = 1.0f / psum;
    float mo[32];
#pragma unroll
    for (int m = 0; m < 32; ++m) mo[m] = 0.f;
    for (int j = 0; j < 20; ++j) {
        float pj = p[j];
#pragma unroll
        for (int m = 0; m < 32; ++m) mo[m] = fmaf(pj, sM[j][m], mo[m]);
    }
    float4* outp = (float4*)(memout + (size_t)t * Mv);
#pragma unroll
    for (int m4 = 0; m4 < 8; ++m4) {
        float4 v;
        v.x = mo[4*m4] * inv; v.y = mo[4*m4+1] * inv;
        v.z = mo[4*m4+2] * inv; v.w = mo[4*m4+3] * inv;
        outp[m4] = v;
    }
}

// ---------------------------------------------------------------------------
// Kernel 2: QKV projection. Per block: one (e,b) and a 64-row t-tile.
// Output tile 64 x 96 ([Q|K|V]); 256 threads, 4x6 register blocking.
// ---------------------------------------------------------------------------
__global__ __launch_bounds__(256) void qkv_kernel(
    const float* __restrict__ hidden,   // [E,B,T,H]
    const float* __restrict__ Wq,       // [E,H,M]
    const float* __restrict__ Wk,
    const float* __restrict__ Wv,
    float* __restrict__ Qo,             // [E,B,T,M]
    float* __restrict__ Ko,
    float* __restrict__ Vo)
{
    __shared__ float sHT[64][68];       // hidden tile transposed [h][t], pad 68
    __shared__ float sW[64][100];       // [h][ Wq(0..31) | Wk(32..63) | Wv(64..95) ]
    int bid  = blockIdx.x;              // 768 = E*B*32
    int tile = bid & 31;
    int b    = (bid >> 5) & 7;
    int e    = bid >> 8;
    int tid  = threadIdx.x;
    size_t row0 = ((size_t)(e * Bv + b)) * Tv + (size_t)tile * 64;
    const float* hbase = hidden + row0 * Hv;

    {   // load + transpose hidden 64x64
        int r  = tid >> 2;
        int c4 = tid & 3;
#pragma unroll
        for (int hh = 0; hh < 4; ++hh) {
            int h4 = c4 + hh * 4;       // float4 index 0..15
            float4 v = ((const float4*)(hbase + (size_t)r * Hv))[h4];
            sHT[h4*4+0][r] = v.x; sHT[h4*4+1][r] = v.y;
            sHT[h4*4+2][r] = v.z; sHT[h4*4+3][r] = v.w;
        }
    }
    {   // load W for this expert
        const float* wq = Wq + (size_t)e * Hv * Mv;
        const float* wk = Wk + (size_t)e * Hv * Mv;
        const float* wv = Wv + (size_t)e * Hv * Mv;
        for (int i = tid; i < Hv * Mv; i += 256) {
            int h = i >> 5, m = i & 31;
            sW[h][m]      = wq[i];
            sW[h][32 + m] = wk[i];
            sW[h][64 + m] = wv[i];
        }
    }
    __syncthreads();

    int ty = tid >> 4, tx = tid & 15;
    float acc[4][6];
#pragma unroll
    for (int i = 0; i < 4; ++i)
#pragma unroll
        for (int j = 0; j < 6; ++j) acc[i][j] = 0.f;

    for (int h = 0; h < 64; ++h) {
        float4 av = *(const float4*)&sHT[h][ty * 4];
        float a[4] = {av.x, av.y, av.z, av.w};
        float bb[6];
#pragma unroll
        for (int j = 0; j < 6; ++j) bb[j] = sW[h][tx * 6 + j];
#pragma unroll
        for (int i = 0; i < 4; ++i)
#pragma unroll
            for (int j = 0; j < 6; ++j) acc[i][j] = fmaf(a[i], bb[j], acc[i][j]);
    }
#pragma unroll
    for (int i = 0; i < 4; ++i) {
        size_t row = row0 + (size_t)(ty * 4 + i);
#pragma unroll
        for (int j = 0; j < 6; ++j) {
            int c = tx * 6 + j;
            float v = acc[i][j];
            if (c < 32)      Qo[row * Mv + c]        = v;
            else if (c < 64) Ko[row * Mv + (c - 32)] = v;
            else             Vo[row * Mv + (c - 64)] = v;
        }
    }
}

// ---------------------------------------------------------------------------
// Kernel 3: flash attention + cosine epilogue.
// Block = 4 waves over the SAME 64 q rows; wave w handles k in [w*512,(w+1)*512).
// One q row per lane; K/V rows are wave-uniform loads (broadcast, no LDS in loop).
// Partials (m, l, O[32]) combined via LDS; wave 0 finalizes + cosine + fp32 store.
// __launch_bounds__(256, 1): min 1 wave/EU -> allocator free up to 512 VGPR.
// R2's (256,3) made the allocator settle at 84 VGPR and SPILL the O[32]/q[32]
// accumulators to scratch (WRITE_SIZE 748 MB/dispatch, VALUBusy 20%).
// Live set here is ~110-130 VGPR -> expect no spill, 3-4 waves/SIMD natural.
// ---------------------------------------------------------------------------
__global__ __launch_bounds__(256, 1) void attn_kernel(
    const float* __restrict__ Qp,       // [E,B,T,M]
    const float* __restrict__ Kp,
    const float* __restrict__ Vp,
    const float* __restrict__ memv,     // [B*T, M]
    float* __restrict__ out)            // [B,T,E] fp32
{
    __shared__ float red[4][64][34];    // [wave][row][ m, l, O[32] ]
    int bid  = blockIdx.x;              // 768
    int tile = bid & 31;
    int b    = (bid >> 5) & 7;
    int e    = bid >> 8;
    int tid  = threadIdx.x;
    int lane = tid & 63;
    int w    = tid >> 6;
    int t    = tile * 64 + lane;
    size_t eb = (size_t)(e * Bv + b);

    const float4* qr = (const float4*)(Qp + (eb * Tv + t) * Mv);
    float q[32];
#pragma unroll
    for (int i = 0; i < 8; ++i) {
        float4 v = qr[i];
        q[4*i] = v.x; q[4*i+1] = v.y; q[4*i+2] = v.z; q[4*i+3] = v.w;
    }
    float O[32];
#pragma unroll
    for (int i = 0; i < 32; ++i) O[i] = 0.f;
    float mI = -3.0e38f, l = 0.f;

    const float* Kb = Kp + eb * Tv * Mv;
    const float* Vb = Vp + eb * Tv * Mv;
    const int k0 = w * 512;

    for (int kc = 0; kc < 512; kc += 16) {
        const float* kch = Kb + (size_t)(k0 + kc) * Mv;
        float s[16];
#pragma unroll
        for (int kk = 0; kk < 16; ++kk) {
            const float4* kr = (const float4*)(kch + kk * Mv);
            float4 k0v = kr[0], k1v = kr[1], k2v = kr[2], k3v = kr[3];
            float4 k4v = kr[4], k5v = kr[5], k6v = kr[6], k7v = kr[7];
            float a0 = q[0]*k0v.x + q[1]*k0v.y + q[2]*k0v.z + q[3]*k0v.w;
            float a1 = q[4]*k1v.x + q[5]*k1v.y + q[6]*k1v.z + q[7]*k1v.w;
            float a2 = q[8]*k2v.x + q[9]*k2v.y + q[10]*k2v.z + q[11]*k2v.w;
            float a3 = q[12]*k3v.x + q[13]*k3v.y + q[14]*k3v.z + q[15]*k3v.w;
            float a4 = q[16]*k4v.x + q[17]*k4v.y + q[18]*k4v.z + q[19]*k4v.w;
            float a5 = q[20]*k5v.x + q[21]*k5v.y + q[22]*k5v.z + q[23]*k5v.w;
            float a6 = q[24]*k6v.x + q[25]*k6v.y + q[26]*k6v.z + q[27]*k6v.w;
            float a7 = q[28]*k7v.x + q[29]*k7v.y + q[30]*k7v.z + q[31]*k7v.w;
            s[kk] = ((a0 + a1) + (a2 + a3)) + ((a4 + a5) + (a6 + a7));
        }
        float cm = s[0];
#pragma unroll
        for (int kk = 1; kk < 16; ++kk) cm = fmaxf(cm, s[kk]);
        float mNew  = fmaxf(mI, cm);
        float alpha = exp2f((mI - mNew) * LOG2E);
        l *= alpha;
#pragma unroll
        for (int i = 0; i < 32; ++i) O[i] *= alpha;
        mI = mNew;

        const float* vch = Vb + (size_t)(k0 + kc) * Mv;
#pragma unroll
        for (int kk = 0; kk < 16; ++kk) {
            float p = exp2f((s[kk] - mNew) * LOG2E);
            l += p;
            const float4* vr = (const float4*)(vch + kk * Mv);
#pragma unroll
            for (int i = 0; i < 8; ++i) {
                float4 v = vr[i];
                O[4*i]   = fmaf(p, v.x, O[4*i]);
                O[4*i+1] = fmaf(p, v.y, O[4*i+1]);
                O[4*i+2] = fmaf(p, v.z, O[4*i+2]);
                O[4*i+3] = fmaf(p, v.w, O[4*i+3]);
            }
        }
    }

    // write per-wave partials
    red[w][lane][0] = mI;
    red[w][lane][1] = l;
#pragma unroll
    for (int i = 0; i < 32; ++i) red[w][lane][2 + i] = O[i];
    __syncthreads();

    if (w == 0) {
        float M = red[0][lane][0];
#pragma unroll
        for (int ww = 1; ww < 4; ++ww) M = fmaxf(M, red[ww][lane][0]);
        float L = 0.f;
        float Of[32];
#pragma unroll
        for (int i = 0; i < 32; ++i) Of[i] = 0.f;
#pragma unroll
        for (int ww = 0; ww < 4; ++ww) {
            float a  = exp2f((red[ww][lane][0] - M) * LOG2E);
            L += red[ww][lane][1] * a;
#pragma unroll
            for (int i = 0; i < 32; ++i)
                Of[i] = fmaf(a, red[ww][lane][2 + i], Of[i]);
        }
        // cosine with memories; out_vec = Of / L
        const float4* mr = (const float4*)(memv + ((size_t)b * Tv + t) * Mv);
        float dot = 0.f, nm = 0.f, no = 0.f;
#pragma unroll
        for (int i = 0; i < 8; ++i) {
            float4 mv = mr[i];
            float m0 = mv.x, m1 = mv.y, m2 = mv.z, m3 = mv.w;
            dot = fmaf(m0, Of[4*i], dot);   dot = fmaf(m1, Of[4*i+1], dot);
            dot = fmaf(m2, Of[4*i+2], dot); dot = fmaf(m3, Of[4*i+3], dot);
            nm  = fmaf(m0, m0, nm); nm = fmaf(m1, m1, nm);
            nm  = fmaf(m2, m2, nm); nm = fmaf(m3, m3, nm);
            no  = fmaf(Of[4*i], Of[4*i], no);     no = fmaf(Of[4*i+1], Of[4*i+1], no);
            no  = fmaf(Of[4*i+2], Of[4*i+2], no); no = fmaf(Of[4*i+3], Of[4*i+3], no);
        }
        float na = fmaxf(sqrtf(nm), 1e-8f);
        float nb = fmaxf(sqrtf(no) / L, 1e-8f);
        float cosv = (dot / L) / (na * nb);
        out[((size_t)b * Tv + t) * Ev + e] = cosv;   // fp32 store (ref output is float32)
    }
}

// ---------------------------------------------------------------------------
extern "C" void kernel_launch(void* const* d_in, const int* in_sizes, int n_in,
                              void* d_out, int out_size, void* d_ws, size_t ws_size,
                              hipStream_t stream) {
    const float* x      = (const float*)d_in[0];   // [B,T,IN]
    const float* hidden = (const float*)d_in[1];   // [E,B,T,H]
    const float* memory = (const float*)d_in[2];   // [S,M]
    const float* Wq     = (const float*)d_in[3];   // [E,H,M]
    const float* Wk     = (const float*)d_in[4];
    const float* Wv     = (const float*)d_in[5];
    const float* iq     = (const float*)d_in[6];   // [IN,M]
    float* out          = (float*)d_out;           // [B,T,E] fp32

    float* ws = (float*)d_ws;
    // workspace layout (floats): memories | Q | K | V  (total 20 MiB)
    const size_t MEMO = 0;
    const size_t QO   = MEMO + (size_t)Bv * Tv * Mv;          //   524288
    const size_t KO   = QO + (size_t)Ev * Bv * Tv * Mv;       // + 1572864
    const size_t VO   = KO + (size_t)Ev * Bv * Tv * Mv;
    float* memout = ws + MEMO;
    float* Qb = ws + QO;
    float* Kb = ws + KO;
    float* Vb = ws + VO;

    mem_kernel<<<(Bv * Tv) / 256, 256, 0, stream>>>(x, memory, iq, memout);
    qkv_kernel<<<Ev * Bv * (Tv / 64), 256, 0, stream>>>(hidden, Wq, Wk, Wv, Qb, Kb, Vb);
    attn_kernel<<<Ev * Bv * (Tv / 64), 256, 0, stream>>>(Qb, Kb, Vb, memout, out);
}

// Round 4
// 404.154 us; speedup vs baseline: 2.8181x; 2.2050x over previous
//
#include <hip/hip_runtime.h>
#include <hip/hip_bf16.h>

// Problem sizes (fixed): B=8, T=2048, H=64, M=32, S=20, E=3, IN=32
#define Bv  8
#define Tv  2048
#define Hv  64
#define Mv  32
#define Sv  20
#define Ev  3
#define INv 32
#define LOG2E 1.44269504088896340736f

// ---------------------------------------------------------------------------
// Kernel 1: memories[b,t,:] = softmax((x@IQ) @ mem^T) @ mem        [B*T, 32]
// ---------------------------------------------------------------------------
__global__ __launch_bounds__(256) void mem_kernel(
    const float* __restrict__ x,        // [B*T, 32]
    const float* __restrict__ memory,   // [20, 32]
    const float* __restrict__ iq,       // [32, 32]
    float* __restrict__ memout)         // [B*T, 32]
{
    __shared__ float sIQ[32][32];
    __shared__ float sM[20][32];
    int tid = threadIdx.x;
    for (int i = tid; i < 32 * 32; i += 256) sIQ[i >> 5][i & 31] = iq[i];
    for (int i = tid; i < 20 * 32; i += 256) sM[i >> 5][i & 31] = memory[i];
    __syncthreads();

    int t = blockIdx.x * 256 + tid;     // token index < B*T
    const float4* xr = (const float4*)(x + (size_t)t * INv);
    float xv[32];
#pragma unroll
    for (int i = 0; i < 8; ++i) {
        float4 v = xr[i];
        xv[4*i] = v.x; xv[4*i+1] = v.y; xv[4*i+2] = v.z; xv[4*i+3] = v.w;
    }
    float qm[32];
#pragma unroll
    for (int m = 0; m < 32; ++m) qm[m] = 0.f;
    for (int i = 0; i < 32; ++i) {
        float xi = xv[i];
#pragma unroll
        for (int m4 = 0; m4 < 8; ++m4) {
            float4 wv = *(const float4*)&sIQ[i][m4 * 4];
            qm[4*m4]   = fmaf(xi, wv.x, qm[4*m4]);
            qm[4*m4+1] = fmaf(xi, wv.y, qm[4*m4+1]);
            qm[4*m4+2] = fmaf(xi, wv.z, qm[4*m4+2]);
            qm[4*m4+3] = fmaf(xi, wv.w, qm[4*m4+3]);
        }
    }
    float sc[20];
#pragma unroll
    for (int j = 0; j < 20; ++j) {
        float acc = 0.f;
#pragma unroll
        for (int m = 0; m < 32; ++m) acc = fmaf(qm[m], sM[j][m], acc);
        sc[j] = acc;
    }
    float mx = sc[0];
#pragma unroll
    for (int j = 1; j < 20; ++j) mx = fmaxf(mx, sc[j]);
    float psum = 0.f, p[20];
#pragma unroll
    for (int j = 0; j < 20; ++j) { p[j] = exp2f((sc[j] - mx) * LOG2E); psum += p[j]; }
    float inv = 1.0f / psum;
    float mo[32];
#pragma unroll
    for (int m = 0; m < 32; ++m) mo[m] = 0.f;
    for (int j = 0; j < 20; ++j) {
        float pj = p[j];
#pragma unroll
        for (int m = 0; m < 32; ++m) mo[m] = fmaf(pj, sM[j][m], mo[m]);
    }
    float4* outp = (float4*)(memout + (size_t)t * Mv);
#pragma unroll
    for (int m4 = 0; m4 < 8; ++m4) {
        float4 v;
        v.x = mo[4*m4] * inv; v.y = mo[4*m4+1] * inv;
        v.z = mo[4*m4+2] * inv; v.w = mo[4*m4+3] * inv;
        outp[m4] = v;
    }
}

// ---------------------------------------------------------------------------
// Kernel 2: QKV projection. Per block: one (e,b) and a 64-row t-tile.
// Output tile 64 x 96 ([Q|K|V]); 256 threads, 4x6 register blocking.
// ---------------------------------------------------------------------------
__global__ __launch_bounds__(256) void qkv_kernel(
    const float* __restrict__ hidden,   // [E,B,T,H]
    const float* __restrict__ Wq,       // [E,H,M]
    const float* __restrict__ Wk,
    const float* __restrict__ Wv,
    float* __restrict__ Qo,             // [E,B,T,M]
    float* __restrict__ Ko,
    float* __restrict__ Vo)
{
    __shared__ float sHT[64][68];       // hidden tile transposed [h][t], pad 68
    __shared__ float sW[64][100];       // [h][ Wq(0..31) | Wk(32..63) | Wv(64..95) ]
    int bid  = blockIdx.x;              // 768 = E*B*32
    int tile = bid & 31;
    int b    = (bid >> 5) & 7;
    int e    = bid >> 8;
    int tid  = threadIdx.x;
    size_t row0 = ((size_t)(e * Bv + b)) * Tv + (size_t)tile * 64;
    const float* hbase = hidden + row0 * Hv;

    {   // load + transpose hidden 64x64
        int r  = tid >> 2;
        int c4 = tid & 3;
#pragma unroll
        for (int hh = 0; hh < 4; ++hh) {
            int h4 = c4 + hh * 4;       // float4 index 0..15
            float4 v = ((const float4*)(hbase + (size_t)r * Hv))[h4];
            sHT[h4*4+0][r] = v.x; sHT[h4*4+1][r] = v.y;
            sHT[h4*4+2][r] = v.z; sHT[h4*4+3][r] = v.w;
        }
    }
    {   // load W for this expert
        const float* wq = Wq + (size_t)e * Hv * Mv;
        const float* wk = Wk + (size_t)e * Hv * Mv;
        const float* wv = Wv + (size_t)e * Hv * Mv;
        for (int i = tid; i < Hv * Mv; i += 256) {
            int h = i >> 5, m = i & 31;
            sW[h][m]      = wq[i];
            sW[h][32 + m] = wk[i];
            sW[h][64 + m] = wv[i];
        }
    }
    __syncthreads();

    int ty = tid >> 4, tx = tid & 15;
    float acc[4][6];
#pragma unroll
    for (int i = 0; i < 4; ++i)
#pragma unroll
        for (int j = 0; j < 6; ++j) acc[i][j] = 0.f;

    for (int h = 0; h < 64; ++h) {
        float4 av = *(const float4*)&sHT[h][ty * 4];
        float a[4] = {av.x, av.y, av.z, av.w};
        float bb[6];
#pragma unroll
        for (int j = 0; j < 6; ++j) bb[j] = sW[h][tx * 6 + j];
#pragma unroll
        for (int i = 0; i < 4; ++i)
#pragma unroll
            for (int j = 0; j < 6; ++j) acc[i][j] = fmaf(a[i], bb[j], acc[i][j]);
    }
#pragma unroll
    for (int i = 0; i < 4; ++i) {
        size_t row = row0 + (size_t)(ty * 4 + i);
#pragma unroll
        for (int j = 0; j < 6; ++j) {
            int c = tx * 6 + j;
            float v = acc[i][j];
            if (c < 32)      Qo[row * Mv + c]        = v;
            else if (c < 64) Ko[row * Mv + (c - 32)] = v;
            else             Vo[row * Mv + (c - 64)] = v;
        }
    }
}

// ---------------------------------------------------------------------------
// async global->LDS copy, 16 B per lane (global_load_lds_dwordx4).
// LDS dst: wave-uniform base + lane*16 (m97/m104 semantics).
// ---------------------------------------------------------------------------
__device__ __forceinline__ void load_lds16(const float* g, float* l) {
    __builtin_amdgcn_global_load_lds(
        (const __attribute__((address_space(1))) void*)g,
        (__attribute__((address_space(3))) void*)l, 16, 0, 0);
}

// ---------------------------------------------------------------------------
// Kernel 3: flash attention + cosine epilogue, LDS-staged K/V (double buffer).
// Block = 4 waves over the SAME 64 q rows; wave w handles k in [w*512,(w+1)*512).
// Per chunk (16 k-rows): stage next chunk via global_load_lds (async, no VGPRs),
// compute current chunk from LDS (broadcast ds_read_b128 + FMA). The barrier's
// vmcnt(0) drain lands after ~2200 cyc of compute -> latency hidden (m97 pattern).
// smem: stage sK[2][4][16][32] + sV[2][4][16][32] (32 KB) ALIASED with
// reduction red[4][64][34] (34816 B) used after the k-loop.
// ---------------------------------------------------------------------------
__global__ __launch_bounds__(256, 1) void attn_kernel(
    const float* __restrict__ Qp,       // [E,B,T,M]
    const float* __restrict__ Kp,
    const float* __restrict__ Vp,
    const float* __restrict__ memv,     // [B*T, M]
    float* __restrict__ out)            // [B,T,E] fp32
{
    __shared__ __align__(16) float smem[8704];   // 34816 B
    int bid  = blockIdx.x;              // 768
    int tile = bid & 31;
    int b    = (bid >> 5) & 7;
    int e    = bid >> 8;
    int tid  = threadIdx.x;
    int lane = tid & 63;
    int w    = tid >> 6;
    int t    = tile * 64 + lane;
    size_t eb = (size_t)(e * Bv + b);

    const float4* qr = (const float4*)(Qp + (eb * Tv + t) * Mv);
    float q[32];
#pragma unroll
    for (int i = 0; i < 8; ++i) {
        float4 v = qr[i];
        q[4*i] = v.x; q[4*i+1] = v.y; q[4*i+2] = v.z; q[4*i+3] = v.w;
    }
    float O[32];
#pragma unroll
    for (int i = 0; i < 32; ++i) O[i] = 0.f;
    float mI = -3.0e38f, l = 0.f;

    const float* Kb = Kp + eb * Tv * Mv;
    const float* Vb = Vp + eb * Tv * Mv;
    const int k0 = w * 512;

    // stage-buffer bases (floats): K: p*2048 + w*512 ; V: 4096 + p*2048 + w*512
    float* sK = smem + w * 512;
    float* sV = smem + 4096 + w * 512;
    // chunk = 16 rows * 32 floats = 512 floats = 2048 B = 2 lds16 instrs (K), 2 (V)

    // preload chunk 0 into buffer p=0
    {
        const float* gk = Kb + (size_t)k0 * Mv;
        const float* gv = Vb + (size_t)k0 * Mv;
        load_lds16(gk + lane * 4,       sK);
        load_lds16(gk + 256 + lane * 4, sK + 256);
        load_lds16(gv + lane * 4,       sV);
        load_lds16(gv + 256 + lane * 4, sV + 256);
    }

    for (int c = 0; c < 32; ++c) {
        int p = c & 1;
        __syncthreads();                 // vmcnt(0) drain: chunk c resident
        if (c + 1 < 32) {                // stage chunk c+1 into buffer p^1 (async)
            const float* gk = Kb + (size_t)(k0 + (c + 1) * 16) * Mv;
            const float* gv = Vb + (size_t)(k0 + (c + 1) * 16) * Mv;
            float* dK = sK + (p ^ 1) * 2048;
            float* dV = sV + (p ^ 1) * 2048;
            load_lds16(gk + lane * 4,       dK);
            load_lds16(gk + 256 + lane * 4, dK + 256);
            load_lds16(gv + lane * 4,       dV);
            load_lds16(gv + 256 + lane * 4, dV + 256);
        }
        const float* kch = sK + p * 2048;
        const float* vch = sV + p * 2048;

        float s[16];
#pragma unroll
        for (int kk = 0; kk < 16; ++kk) {
            const float4* kr = (const float4*)(kch + kk * Mv);
            float4 k0v = kr[0], k1v = kr[1], k2v = kr[2], k3v = kr[3];
            float4 k4v = kr[4], k5v = kr[5], k6v = kr[6], k7v = kr[7];
            float a0 = q[0]*k0v.x + q[1]*k0v.y + q[2]*k0v.z + q[3]*k0v.w;
            float a1 = q[4]*k1v.x + q[5]*k1v.y + q[6]*k1v.z + q[7]*k1v.w;
            float a2 = q[8]*k2v.x + q[9]*k2v.y + q[10]*k2v.z + q[11]*k2v.w;
            float a3 = q[12]*k3v.x + q[13]*k3v.y + q[14]*k3v.z + q[15]*k3v.w;
            float a4 = q[16]*k4v.x + q[17]*k4v.y + q[18]*k4v.z + q[19]*k4v.w;
            float a5 = q[20]*k5v.x + q[21]*k5v.y + q[22]*k5v.z + q[23]*k5v.w;
            float a6 = q[24]*k6v.x + q[25]*k6v.y + q[26]*k6v.z + q[27]*k6v.w;
            float a7 = q[28]*k7v.x + q[29]*k7v.y + q[30]*k7v.z + q[31]*k7v.w;
            s[kk] = ((a0 + a1) + (a2 + a3)) + ((a4 + a5) + (a6 + a7));
        }
        float cm = s[0];
#pragma unroll
        for (int kk = 1; kk < 16; ++kk) cm = fmaxf(cm, s[kk]);
        float mNew  = fmaxf(mI, cm);
        float alpha = exp2f((mI - mNew) * LOG2E);
        l *= alpha;
#pragma unroll
        for (int i = 0; i < 32; ++i) O[i] *= alpha;
        mI = mNew;

#pragma unroll
        for (int kk = 0; kk < 16; ++kk) {
            float p2 = exp2f((s[kk] - mNew) * LOG2E);
            l += p2;
            const float4* vr = (const float4*)(vch + kk * Mv);
#pragma unroll
            for (int i = 0; i < 8; ++i) {
                float4 v = vr[i];
                O[4*i]   = fmaf(p2, v.x, O[4*i]);
                O[4*i+1] = fmaf(p2, v.y, O[4*i+1]);
                O[4*i+2] = fmaf(p2, v.z, O[4*i+2]);
                O[4*i+3] = fmaf(p2, v.w, O[4*i+3]);
            }
        }
    }

    // ---- reduction: overlay red[4][64][34] on smem (stage buffers now dead)
    __syncthreads();
    float (*red)[64][34] = (float (*)[64][34])smem;
    red[w][lane][0] = mI;
    red[w][lane][1] = l;
#pragma unroll
    for (int i = 0; i < 32; ++i) red[w][lane][2 + i] = O[i];
    __syncthreads();

    if (w == 0) {
        float M = red[0][lane][0];
#pragma unroll
        for (int ww = 1; ww < 4; ++ww) M = fmaxf(M, red[ww][lane][0]);
        float L = 0.f;
        float Of[32];
#pragma unroll
        for (int i = 0; i < 32; ++i) Of[i] = 0.f;
#pragma unroll
        for (int ww = 0; ww < 4; ++ww) {
            float a  = exp2f((red[ww][lane][0] - M) * LOG2E);
            L += red[ww][lane][1] * a;
#pragma unroll
            for (int i = 0; i < 32; ++i)
                Of[i] = fmaf(a, red[ww][lane][2 + i], Of[i]);
        }
        // cosine with memories; out_vec = Of / L
        const float4* mr = (const float4*)(memv + ((size_t)b * Tv + t) * Mv);
        float dot = 0.f, nm = 0.f, no = 0.f;
#pragma unroll
        for (int i = 0; i < 8; ++i) {
            float4 mv = mr[i];
            float m0 = mv.x, m1 = mv.y, m2 = mv.z, m3 = mv.w;
            dot = fmaf(m0, Of[4*i], dot);   dot = fmaf(m1, Of[4*i+1], dot);
            dot = fmaf(m2, Of[4*i+2], dot); dot = fmaf(m3, Of[4*i+3], dot);
            nm  = fmaf(m0, m0, nm); nm = fmaf(m1, m1, nm);
            nm  = fmaf(m2, m2, nm); nm = fmaf(m3, m3, nm);
            no  = fmaf(Of[4*i], Of[4*i], no);     no = fmaf(Of[4*i+1], Of[4*i+1], no);
            no  = fmaf(Of[4*i+2], Of[4*i+2], no); no = fmaf(Of[4*i+3], Of[4*i+3], no);
        }
        float na = fmaxf(sqrtf(nm), 1e-8f);
        float nb = fmaxf(sqrtf(no) / L, 1e-8f);
        float cosv = (dot / L) / (na * nb);
        out[((size_t)b * Tv + t) * Ev + e] = cosv;   // fp32 store (ref output is float32)
    }
}

// ---------------------------------------------------------------------------
extern "C" void kernel_launch(void* const* d_in, const int* in_sizes, int n_in,
                              void* d_out, int out_size, void* d_ws, size_t ws_size,
                              hipStream_t stream) {
    const float* x      = (const float*)d_in[0];   // [B,T,IN]
    const float* hidden = (const float*)d_in[1];   // [E,B,T,H]
    const float* memory = (const float*)d_in[2];   // [S,M]
    const float* Wq     = (const float*)d_in[3];   // [E,H,M]
    const float* Wk     = (const float*)d_in[4];
    const float* Wv     = (const float*)d_in[5];
    const float* iq     = (const float*)d_in[6];   // [IN,M]
    float* out          = (float*)d_out;           // [B,T,E] fp32

    float* ws = (float*)d_ws;
    // workspace layout (floats): memories | Q | K | V  (total 20 MiB)
    const size_t MEMO = 0;
    const size_t QO   = MEMO + (size_t)Bv * Tv * Mv;          //   524288
    const size_t KO   = QO + (size_t)Ev * Bv * Tv * Mv;       // + 1572864
    const size_t VO   = KO + (size_t)Ev * Bv * Tv * Mv;
    float* memout = ws + MEMO;
    float* Qb = ws + QO;
    float* Kb = ws + KO;
    float* Vb = ws + VO;

    mem_kernel<<<(Bv * Tv) / 256, 256, 0, stream>>>(x, memory, iq, memout);
    qkv_kernel<<<Ev * Bv * (Tv / 64), 256, 0, stream>>>(hidden, Wq, Wk, Wv, Qb, Kb, Vb);
    attn_kernel<<<Ev * Bv * (Tv / 64), 256, 0, stream>>>(Qb, Kb, Vb, memout, out);
}

// Round 6
// 234.844 us; speedup vs baseline: 4.8497x; 1.7209x over previous
//
#include <hip/hip_runtime.h>
#include <hip/hip_bf16.h>

// Problem sizes (fixed): B=8, T=2048, H=64, M=32, S=20, E=3, IN=32
#define Bv  8
#define Tv  2048
#define Hv  64
#define Mv  32
#define Sv  20
#define Ev  3
#define INv 32
#define LOG2E 1.44269504088896340736f

typedef __attribute__((ext_vector_type(8))) _Float16 half8;
typedef __attribute__((ext_vector_type(2))) __fp16 fp16x2;   // native type of cvt_pkrtz
typedef __attribute__((ext_vector_type(4))) float float4v;

// ---------------------------------------------------------------------------
// Kernel 1: memories[b,t,:] = softmax((x@IQ) @ mem^T) @ mem        [B*T, 32]
// (unchanged from R4 — fp32, ~8 us)
// ---------------------------------------------------------------------------
__global__ __launch_bounds__(256) void mem_kernel(
    const float* __restrict__ x,
    const float* __restrict__ memory,
    const float* __restrict__ iq,
    float* __restrict__ memout)
{
    __shared__ float sIQ[32][32];
    __shared__ float sM[20][32];
    int tid = threadIdx.x;
    for (int i = tid; i < 32 * 32; i += 256) sIQ[i >> 5][i & 31] = iq[i];
    for (int i = tid; i < 20 * 32; i += 256) sM[i >> 5][i & 31] = memory[i];
    __syncthreads();

    int t = blockIdx.x * 256 + tid;
    const float4* xr = (const float4*)(x + (size_t)t * INv);
    float xv[32];
#pragma unroll
    for (int i = 0; i < 8; ++i) {
        float4 v = xr[i];
        xv[4*i] = v.x; xv[4*i+1] = v.y; xv[4*i+2] = v.z; xv[4*i+3] = v.w;
    }
    float qm[32];
#pragma unroll
    for (int m = 0; m < 32; ++m) qm[m] = 0.f;
    for (int i = 0; i < 32; ++i) {
        float xi = xv[i];
#pragma unroll
        for (int m4 = 0; m4 < 8; ++m4) {
            float4 wv = *(const float4*)&sIQ[i][m4 * 4];
            qm[4*m4]   = fmaf(xi, wv.x, qm[4*m4]);
            qm[4*m4+1] = fmaf(xi, wv.y, qm[4*m4+1]);
            qm[4*m4+2] = fmaf(xi, wv.z, qm[4*m4+2]);
            qm[4*m4+3] = fmaf(xi, wv.w, qm[4*m4+3]);
        }
    }
    float sc[20];
#pragma unroll
    for (int j = 0; j < 20; ++j) {
        float acc = 0.f;
#pragma unroll
        for (int m = 0; m < 32; ++m) acc = fmaf(qm[m], sM[j][m], acc);
        sc[j] = acc;
    }
    float mx = sc[0];
#pragma unroll
    for (int j = 1; j < 20; ++j) mx = fmaxf(mx, sc[j]);
    float psum = 0.f, p[20];
#pragma unroll
    for (int j = 0; j < 20; ++j) { p[j] = exp2f((sc[j] - mx) * LOG2E); psum += p[j]; }
    float inv = 1.0f / psum;
    float mo[32];
#pragma unroll
    for (int m = 0; m < 32; ++m) mo[m] = 0.f;
    for (int j = 0; j < 20; ++j) {
        float pj = p[j];
#pragma unroll
        for (int m = 0; m < 32; ++m) mo[m] = fmaf(pj, sM[j][m], mo[m]);
    }
    float4* outp = (float4*)(memout + (size_t)t * Mv);
#pragma unroll
    for (int m4 = 0; m4 < 8; ++m4) {
        float4 v;
        v.x = mo[4*m4] * inv; v.y = mo[4*m4+1] * inv;
        v.z = mo[4*m4+2] * inv; v.w = mo[4*m4+3] * inv;
        outp[m4] = v;
    }
}

// ---------------------------------------------------------------------------
// Kernel 2: QKV projection -> f16 hi/lo split planes for MFMA consumption.
//   Qh/Ql, Kh/Kl: [EB][T][32] f16    Vth/Vtl: [EB][32][T] f16 (transposed)
// hi = f16(v), lo = f16(v - hi): 2-term split, residual ~2^-22 relative.
// ---------------------------------------------------------------------------
__global__ __launch_bounds__(256) void qkv_kernel(
    const float* __restrict__ hidden,
    const float* __restrict__ Wq,
    const float* __restrict__ Wk,
    const float* __restrict__ Wv,
    _Float16* __restrict__ Qh, _Float16* __restrict__ Ql,
    _Float16* __restrict__ Kh, _Float16* __restrict__ Kl,
    _Float16* __restrict__ Vth, _Float16* __restrict__ Vtl)
{
    __shared__ float sHT[64][68];
    __shared__ float sW[64][100];
    int bid  = blockIdx.x;              // 768 = E*B*32
    int tile = bid & 31;
    int b    = (bid >> 5) & 7;
    int e    = bid >> 8;
    int tid  = threadIdx.x;
    size_t eb = (size_t)(e * Bv + b);
    size_t row0 = eb * Tv + (size_t)tile * 64;
    const float* hbase = hidden + row0 * Hv;

    {
        int r  = tid >> 2;
        int c4 = tid & 3;
#pragma unroll
        for (int hh = 0; hh < 4; ++hh) {
            int h4 = c4 + hh * 4;
            float4 v = ((const float4*)(hbase + (size_t)r * Hv))[h4];
            sHT[h4*4+0][r] = v.x; sHT[h4*4+1][r] = v.y;
            sHT[h4*4+2][r] = v.z; sHT[h4*4+3][r] = v.w;
        }
    }
    {
        const float* wq = Wq + (size_t)e * Hv * Mv;
        const float* wk = Wk + (size_t)e * Hv * Mv;
        const float* wv = Wv + (size_t)e * Hv * Mv;
        for (int i = tid; i < Hv * Mv; i += 256) {
            int h = i >> 5, m = i & 31;
            sW[h][m]      = wq[i];
            sW[h][32 + m] = wk[i];
            sW[h][64 + m] = wv[i];
        }
    }
    __syncthreads();

    int ty = tid >> 4, tx = tid & 15;
    float acc[4][6];
#pragma unroll
    for (int i = 0; i < 4; ++i)
#pragma unroll
        for (int j = 0; j < 6; ++j) acc[i][j] = 0.f;

    for (int h = 0; h < 64; ++h) {
        float4 av = *(const float4*)&sHT[h][ty * 4];
        float a[4] = {av.x, av.y, av.z, av.w};
        float bb[6];
#pragma unroll
        for (int j = 0; j < 6; ++j) bb[j] = sW[h][tx * 6 + j];
#pragma unroll
        for (int i = 0; i < 4; ++i)
#pragma unroll
            for (int j = 0; j < 6; ++j) acc[i][j] = fmaf(a[i], bb[j], acc[i][j]);
    }
#pragma unroll
    for (int i = 0; i < 4; ++i) {
        int tloc = tile * 64 + ty * 4 + i;          // t within [0,2048)
        size_t rowg = eb * Tv + (size_t)tloc;       // row in [EB*T)
#pragma unroll
        for (int j = 0; j < 6; ++j) {
            int c = tx * 6 + j;
            float v = acc[i][j];
            _Float16 h16 = (_Float16)v;
            _Float16 l16 = (_Float16)(v - (float)h16);
            if (c < 32) {
                Qh[rowg * 32 + c] = h16;
                Ql[rowg * 32 + c] = l16;
            } else if (c < 64) {
                Kh[rowg * 32 + (c - 32)] = h16;
                Kl[rowg * 32 + (c - 32)] = l16;
            } else {
                size_t vi = (eb * 32 + (size_t)(c - 64)) * Tv + tloc;
                Vth[vi] = h16;
                Vtl[vi] = l16;
            }
        }
    }
}

// ---------------------------------------------------------------------------
// Kernel 3: MFMA flash attention + cosine epilogue (split-f16, fp32-grade).
// Block = 4 waves; wave w owns q rows [q0w, q0w+16). All waves share staged
// K/V chunks (64 keys). Per chunk:
//   S^T = K*Q^T via 3-term split mfma_16x16x32_f16  (C-layout: q = lane&15!)
//   online softmax: 2x shfl_xor(16,32) for row max/sum (replicated per quad)
//   P (f16) -> per-wave LDS (C-layout b64 writes) -> A-layout b128 reads
//   O += P*Vh + P*Vl  (V^T hi/lo B-frags from LDS)
// LDS rows padded (K:80B, V^T:144B, P:136B) -> ~2-way max bank aliasing (free).
// ---------------------------------------------------------------------------
__global__ __launch_bounds__(256, 1) void attn_kernel(
    const _Float16* __restrict__ Qh, const _Float16* __restrict__ Ql,
    const _Float16* __restrict__ Kh, const _Float16* __restrict__ Kl,
    const _Float16* __restrict__ Vth, const _Float16* __restrict__ Vtl,
    const float* __restrict__ memv,
    float* __restrict__ out)
{
    __shared__ __align__(16) char smem[28160];
    const int KH = 0;        // K_hi: 64 rows x 80 B
    const int KL = 5120;     // K_lo
    const int VH = 10240;    // V^T_hi: 32 rows x 144 B
    const int VL = 14848;    // V^T_lo
    const int PW = 19456;    // P: 4 waves x 16 rows x 136 B

    int bid  = blockIdx.x;              // 768
    int tile = bid & 31;
    int b    = (bid >> 5) & 7;
    int e    = bid >> 8;
    int tid  = threadIdx.x;
    int lane = tid & 63;
    int w    = tid >> 6;
    int quad = lane >> 4;
    int l15  = lane & 15;
    size_t eb = (size_t)(e * Bv + b);
    int q0 = tile * 64 + w * 16;        // wave's 16 q-rows

    // Q B-frags (B[k=d][n=q]: lane reads Q[q0+l15][quad*8 .. +7]), once.
    size_t qoff = (eb * Tv + (size_t)(q0 + l15)) * 32 + quad * 8;
    half8 qH = *(const half8*)(Qh + qoff);
    half8 qL = *(const half8*)(Ql + qoff);

    float4v O0 = {0.f, 0.f, 0.f, 0.f};  // O[q=quad*4+r][d=l15]
    float4v O1 = {0.f, 0.f, 0.f, 0.f};  // O[q=quad*4+r][d=16+l15]
    float m_run = -3.0e38f, l_run = 0.f;

    // staging assignment: wave 0->K_hi, 1->K_lo, 2->V^T_hi, 3->V^T_lo
    const _Float16* gsrc = (w == 0) ? Kh : (w == 1) ? Kl : (w == 2) ? Vth : Vtl;
    int ldsbase = (w == 0) ? KH : (w == 1) ? KL : (w == 2) ? VH : VL;
    float4 g[4];

    // preload chunk 0
    {
        int c0 = 0;
        if (w < 2) {
#pragma unroll
            for (int i = 0; i < 4; ++i) {
                int rowc = i * 16 + (lane >> 2), piece = lane & 3;
                g[i] = *(const float4*)(gsrc + (eb * Tv + (size_t)(c0 + rowc)) * 32 + piece * 8);
            }
        } else {
#pragma unroll
            for (int i = 0; i < 4; ++i) {
                int d = i * 8 + (lane >> 3), piece = lane & 7;
                g[i] = *(const float4*)(gsrc + (eb * 32 + (size_t)d) * Tv + c0 + piece * 8);
            }
        }
    }

    for (int c = 0; c < 32; ++c) {
        __syncthreads();                 // prev chunk fully consumed
        if (w < 2) {
#pragma unroll
            for (int i = 0; i < 4; ++i) {
                int rowc = i * 16 + (lane >> 2), piece = lane & 3;
                *(float4*)(smem + ldsbase + rowc * 80 + piece * 16) = g[i];
            }
        } else {
#pragma unroll
            for (int i = 0; i < 4; ++i) {
                int d = i * 8 + (lane >> 3), piece = lane & 7;
                *(float4*)(smem + ldsbase + d * 144 + piece * 16) = g[i];
            }
        }
        __syncthreads();                 // chunk c visible
        if (c + 1 < 32) {                // prefetch chunk c+1 into regs
            int c0 = (c + 1) * 64;
            if (w < 2) {
#pragma unroll
                for (int i = 0; i < 4; ++i) {
                    int rowc = i * 16 + (lane >> 2), piece = lane & 3;
                    g[i] = *(const float4*)(gsrc + (eb * Tv + (size_t)(c0 + rowc)) * 32 + piece * 8);
                }
            } else {
#pragma unroll
                for (int i = 0; i < 4; ++i) {
                    int d = i * 8 + (lane >> 3), piece = lane & 7;
                    g[i] = *(const float4*)(gsrc + (eb * 32 + (size_t)d) * Tv + c0 + piece * 8);
                }
            }
        }

        // ---- S^T = K * Q^T : 4 key-subtiles x 3 split terms
        float s[4][4];
        float cmax = -3.0e38f;
#pragma unroll
        for (int tau = 0; tau < 4; ++tau) {
            int key = tau * 16 + l15;    // A-frag m = l15
            half8 aH = *(const half8*)(smem + KH + key * 80 + quad * 16);
            half8 aL = *(const half8*)(smem + KL + key * 80 + quad * 16);
            float4v acc = {0.f, 0.f, 0.f, 0.f};
            acc = __builtin_amdgcn_mfma_f32_16x16x32_f16(aH, qL, acc, 0, 0, 0);
            acc = __builtin_amdgcn_mfma_f32_16x16x32_f16(aL, qH, acc, 0, 0, 0);
            acc = __builtin_amdgcn_mfma_f32_16x16x32_f16(aH, qH, acc, 0, 0, 0);
#pragma unroll
            for (int r = 0; r < 4; ++r) {
                s[tau][r] = acc[r];      // S^T[key=tau*16+quad*4+r][q=l15]
                cmax = fmaxf(cmax, acc[r]);
            }
        }
        // row max across quads (replicated state at q=l15 in every quad)
        cmax = fmaxf(cmax, __shfl_xor(cmax, 16));
        cmax = fmaxf(cmax, __shfl_xor(cmax, 32));
        float mNew  = fmaxf(m_run, cmax);
        float alpha = exp2f((m_run - mNew) * LOG2E);
        float p[4][4];
        float psum = 0.f;
#pragma unroll
        for (int tau = 0; tau < 4; ++tau)
#pragma unroll
            for (int r = 0; r < 4; ++r) {
                p[tau][r] = exp2f((s[tau][r] - mNew) * LOG2E);
                psum += p[tau][r];
            }
        psum += __shfl_xor(psum, 16);
        psum += __shfl_xor(psum, 32);
        l_run = l_run * alpha + psum;
        m_run = mNew;

        // rescale O (rows q=quad*4+r need that row's alpha)
#pragma unroll
        for (int r = 0; r < 4; ++r) {
            float ar = __shfl(alpha, quad * 4 + r, 16);
            O0[r] *= ar;
            O1[r] *= ar;
        }

        // ---- P (f16) -> per-wave LDS: rows q=l15, keys tau*16+quad*4 .. +3
        char* pw = smem + PW + w * 2176 + l15 * 136;
#pragma unroll
        for (int tau = 0; tau < 4; ++tau) {
            fp16x2 h01 = __builtin_amdgcn_cvt_pkrtz(p[tau][0], p[tau][1]);
            fp16x2 h23 = __builtin_amdgcn_cvt_pkrtz(p[tau][2], p[tau][3]);
            uint2 u;
            u.x = __builtin_bit_cast(unsigned int, h01);
            u.y = __builtin_bit_cast(unsigned int, h23);
            *(uint2*)(pw + tau * 32 + quad * 8) = u;
        }
        __asm__ volatile("" ::: "memory");  // keep ds_write before ds_read (same wave, HW in-order)

        // ---- O += P * V : A = P[q][key], B = V^T (hi+lo), 2 k-steps x 2 d-tiles
#pragma unroll
        for (int ks = 0; ks < 2; ++ks) {
            half8 pA  = *(const half8*)(pw + ks * 64 + quad * 16);
            half8 v0H = *(const half8*)(smem + VH + l15 * 144 + ks * 64 + quad * 16);
            half8 v0L = *(const half8*)(smem + VL + l15 * 144 + ks * 64 + quad * 16);
            half8 v1H = *(const half8*)(smem + VH + (16 + l15) * 144 + ks * 64 + quad * 16);
            half8 v1L = *(const half8*)(smem + VL + (16 + l15) * 144 + ks * 64 + quad * 16);
            O0 = __builtin_amdgcn_mfma_f32_16x16x32_f16(pA, v0H, O0, 0, 0, 0);
            O0 = __builtin_amdgcn_mfma_f32_16x16x32_f16(pA, v0L, O0, 0, 0, 0);
            O1 = __builtin_amdgcn_mfma_f32_16x16x32_f16(pA, v1H, O1, 0, 0, 0);
            O1 = __builtin_amdgcn_mfma_f32_16x16x32_f16(pA, v1L, O1, 0, 0, 0);
        }
    }

    // ---- epilogue: cosine(memories, O/l) per row
    const float* mb = memv + (size_t)b * Tv * 32;
    float dotr[4], nor[4], nmr[4], lf[4];
#pragma unroll
    for (int r = 0; r < 4; ++r) {
        int trow = q0 + quad * 4 + r;
        float mv0 = mb[(size_t)trow * 32 + l15];
        float mv1 = mb[(size_t)trow * 32 + 16 + l15];
        float d  = O0[r] * mv0 + O1[r] * mv1;
        float n  = O0[r] * O0[r] + O1[r] * O1[r];
        float nm = mv0 * mv0 + mv1 * mv1;
#pragma unroll
        for (int delta = 1; delta < 16; delta <<= 1) {
            d  += __shfl_xor(d,  delta);
            n  += __shfl_xor(n,  delta);
            nm += __shfl_xor(nm, delta);
        }
        dotr[r] = d; nor[r] = n; nmr[r] = nm;
        lf[r] = __shfl(l_run, quad * 4 + r, 16);
    }
    if (l15 < 4) {
        int r = l15;
        float linv = 1.0f / lf[r];
        float na = fmaxf(sqrtf(nmr[r]), 1e-8f);
        float nb = fmaxf(sqrtf(nor[r]) * linv, 1e-8f);
        float cosv = (dotr[r] * linv) / (na * nb);
        int trow = q0 + quad * 4 + r;
        out[((size_t)b * Tv + trow) * Ev + e] = cosv;
    }
}

// ---------------------------------------------------------------------------
extern "C" void kernel_launch(void* const* d_in, const int* in_sizes, int n_in,
                              void* d_out, int out_size, void* d_ws, size_t ws_size,
                              hipStream_t stream) {
    const float* x      = (const float*)d_in[0];
    const float* hidden = (const float*)d_in[1];
    const float* memory = (const float*)d_in[2];
    const float* Wq     = (const float*)d_in[3];
    const float* Wk     = (const float*)d_in[4];
    const float* Wv     = (const float*)d_in[5];
    const float* iq     = (const float*)d_in[6];
    float* out          = (float*)d_out;           // [B,T,E] fp32

    char* ws = (char*)d_ws;
    // layout (bytes): memout f32 (2 MiB) | 6 f16 planes a 3 MiB = 20 MiB
    const size_t PLANE = (size_t)Ev * Bv * Tv * 32 * 2;   // 3,145,728 B
    float*    memout = (float*)ws;
    _Float16* Qh  = (_Float16*)(ws + 2097152);
    _Float16* Ql  = (_Float16*)(ws + 2097152 + PLANE);
    _Float16* Kh  = (_Float16*)(ws + 2097152 + 2 * PLANE);
    _Float16* Kl  = (_Float16*)(ws + 2097152 + 3 * PLANE);
    _Float16* Vth = (_Float16*)(ws + 2097152 + 4 * PLANE);
    _Float16* Vtl = (_Float16*)(ws + 2097152 + 5 * PLANE);

    mem_kernel<<<(Bv * Tv) / 256, 256, 0, stream>>>(x, memory, iq, memout);
    qkv_kernel<<<Ev * Bv * (Tv / 64), 256, 0, stream>>>(hidden, Wq, Wk, Wv,
                                                        Qh, Ql, Kh, Kl, Vth, Vtl);
    attn_kernel<<<Ev * Bv * (Tv / 64), 256, 0, stream>>>(Qh, Ql, Kh, Kl, Vth, Vtl,
                                                         memout, out);
}

// Round 7
// 180.670 us; speedup vs baseline: 6.3039x; 1.2999x over previous
//
#include <hip/hip_runtime.h>
#include <hip/hip_bf16.h>

// Problem sizes (fixed): B=8, T=2048, H=64, M=32, S=20, E=3, IN=32
#define Bv  8
#define Tv  2048
#define Hv  64
#define Mv  32
#define Sv  20
#define Ev  3
#define INv 32
#define LOG2E 1.44269504088896340736f

typedef __attribute__((ext_vector_type(8))) _Float16 half8;
typedef __attribute__((ext_vector_type(2))) __fp16 fp16x2;
typedef __attribute__((ext_vector_type(4))) float float4v;

// ---------------------------------------------------------------------------
// Kernel 1: memories[b,t,:] = softmax((x@IQ) @ mem^T) @ mem        [B*T, 32]
// (unchanged — ~8 us)
// ---------------------------------------------------------------------------
__global__ __launch_bounds__(256) void mem_kernel(
    const float* __restrict__ x,
    const float* __restrict__ memory,
    const float* __restrict__ iq,
    float* __restrict__ memout)
{
    __shared__ float sIQ[32][32];
    __shared__ float sM[20][32];
    int tid = threadIdx.x;
    for (int i = tid; i < 32 * 32; i += 256) sIQ[i >> 5][i & 31] = iq[i];
    for (int i = tid; i < 20 * 32; i += 256) sM[i >> 5][i & 31] = memory[i];
    __syncthreads();

    int t = blockIdx.x * 256 + tid;
    const float4* xr = (const float4*)(x + (size_t)t * INv);
    float xv[32];
#pragma unroll
    for (int i = 0; i < 8; ++i) {
        float4 v = xr[i];
        xv[4*i] = v.x; xv[4*i+1] = v.y; xv[4*i+2] = v.z; xv[4*i+3] = v.w;
    }
    float qm[32];
#pragma unroll
    for (int m = 0; m < 32; ++m) qm[m] = 0.f;
    for (int i = 0; i < 32; ++i) {
        float xi = xv[i];
#pragma unroll
        for (int m4 = 0; m4 < 8; ++m4) {
            float4 wv = *(const float4*)&sIQ[i][m4 * 4];
            qm[4*m4]   = fmaf(xi, wv.x, qm[4*m4]);
            qm[4*m4+1] = fmaf(xi, wv.y, qm[4*m4+1]);
            qm[4*m4+2] = fmaf(xi, wv.z, qm[4*m4+2]);
            qm[4*m4+3] = fmaf(xi, wv.w, qm[4*m4+3]);
        }
    }
    float sc[20];
#pragma unroll
    for (int j = 0; j < 20; ++j) {
        float acc = 0.f;
#pragma unroll
        for (int m = 0; m < 32; ++m) acc = fmaf(qm[m], sM[j][m], acc);
        sc[j] = acc;
    }
    float mx = sc[0];
#pragma unroll
    for (int j = 1; j < 20; ++j) mx = fmaxf(mx, sc[j]);
    float psum = 0.f, p[20];
#pragma unroll
    for (int j = 0; j < 20; ++j) { p[j] = exp2f((sc[j] - mx) * LOG2E); psum += p[j]; }
    float inv = 1.0f / psum;
    float mo[32];
#pragma unroll
    for (int m = 0; m < 32; ++m) mo[m] = 0.f;
    for (int j = 0; j < 20; ++j) {
        float pj = p[j];
#pragma unroll
        for (int m = 0; m < 32; ++m) mo[m] = fmaf(pj, sM[j][m], mo[m]);
    }
    float4* outp = (float4*)(memout + (size_t)t * Mv);
#pragma unroll
    for (int m4 = 0; m4 < 8; ++m4) {
        float4 v;
        v.x = mo[4*m4] * inv; v.y = mo[4*m4+1] * inv;
        v.z = mo[4*m4+2] * inv; v.w = mo[4*m4+3] * inv;
        outp[m4] = v;
    }
}

// ---------------------------------------------------------------------------
// Kernel 2: QKV projection -> f16 hi/lo planes, LDS-staged coalesced stores.
// Global layouts (per eb = e*8+b, per 64-row chunk "tile"):
//   Qh/Ql : linear [EB][T][32]                       (attn reads per-lane)
//   Kh/Kl : chunk-contiguous 4 KB: row r (0..63) x 64 B, 16B-block q stored
//           at position ((q + r) & 3)                 (DMA-able, conflict-free reads)
//   Vth/Vtl: chunk-contiguous 4 KB: row d (0..31) x 128 B (64 keys f16),
//           16B-block c8 (0..7) stored at ((c8 + d) & 7)
// ---------------------------------------------------------------------------
__global__ __launch_bounds__(256) void qkv_kernel(
    const float* __restrict__ hidden,
    const float* __restrict__ Wq,
    const float* __restrict__ Wk,
    const float* __restrict__ Wv,
    _Float16* __restrict__ Qh, _Float16* __restrict__ Ql,
    _Float16* __restrict__ Kh, _Float16* __restrict__ Kl,
    _Float16* __restrict__ Vth, _Float16* __restrict__ Vtl)
{
    // aliased LDS: compute phase uses sHT(64x68 f32, 17408 B) + sW(64x100 f32,
    // 25600 B) = 43008 B; output-staging phase reuses bytes 0..24575.
    __shared__ __align__(16) char qsm[43008];
    float* sHT = (float*)qsm;                    // [h][t] stride 68
    float* sW  = (float*)(qsm + 17408);          // [h][96+pad] stride 100

    int bid  = blockIdx.x;              // 768 = E*B*32
    int tile = bid & 31;
    int b    = (bid >> 5) & 7;
    int e    = bid >> 8;
    int tid  = threadIdx.x;
    size_t eb = (size_t)(e * Bv + b);
    size_t row0 = eb * Tv + (size_t)tile * 64;
    const float* hbase = hidden + row0 * Hv;

    {
        int r  = tid >> 2;
        int c4 = tid & 3;
#pragma unroll
        for (int hh = 0; hh < 4; ++hh) {
            int h4 = c4 + hh * 4;
            float4 v = ((const float4*)(hbase + (size_t)r * Hv))[h4];
            sHT[(h4*4+0)*68 + r] = v.x; sHT[(h4*4+1)*68 + r] = v.y;
            sHT[(h4*4+2)*68 + r] = v.z; sHT[(h4*4+3)*68 + r] = v.w;
        }
    }
    {
        const float* wq = Wq + (size_t)e * Hv * Mv;
        const float* wk = Wk + (size_t)e * Hv * Mv;
        const float* wv = Wv + (size_t)e * Hv * Mv;
        for (int i = tid; i < Hv * Mv; i += 256) {
            int h = i >> 5, m = i & 31;
            sW[h*100 + m]      = wq[i];
            sW[h*100 + 32 + m] = wk[i];
            sW[h*100 + 64 + m] = wv[i];
        }
    }
    __syncthreads();

    int ty = tid >> 4, tx = tid & 15;
    float acc[4][6];
#pragma unroll
    for (int i = 0; i < 4; ++i)
#pragma unroll
        for (int j = 0; j < 6; ++j) acc[i][j] = 0.f;

    for (int h = 0; h < 64; ++h) {
        float4 av = *(const float4*)&sHT[h*68 + ty * 4];
        float a[4] = {av.x, av.y, av.z, av.w};
        float bb[6];
#pragma unroll
        for (int j = 0; j < 6; ++j) bb[j] = sW[h*100 + tx * 6 + j];
#pragma unroll
        for (int i = 0; i < 4; ++i)
#pragma unroll
            for (int j = 0; j < 6; ++j) acc[i][j] = fmaf(a[i], bb[j], acc[i][j]);
    }

    // ---- stage f16 hi/lo into LDS (compute reads done -> barrier, reuse)
    __syncthreads();
    char* sQh = qsm;            // 4096 B each, in order Qh Ql Kh Kl Vh Vl
    char* sQl = qsm + 4096;
    char* sKh = qsm + 8192;
    char* sKl = qsm + 12288;
    char* sVh = qsm + 16384;
    char* sVl = qsm + 20480;
#pragma unroll
    for (int i = 0; i < 4; ++i) {
        int row = ty * 4 + i;               // row within 64-chunk
#pragma unroll
        for (int j = 0; j < 6; ++j) {
            int c = tx * 6 + j;
            float v = acc[i][j];
            _Float16 h16 = (_Float16)v;
            _Float16 l16 = (_Float16)(v - (float)h16);
            if (c < 32) {
                *(_Float16*)(sQh + row * 64 + c * 2) = h16;
                *(_Float16*)(sQl + row * 64 + c * 2) = l16;
            } else if (c < 64) {
                int m = c - 32, q = m >> 3, wi = m & 7;
                int off = row * 64 + (((q + row) & 3) << 4) + wi * 2;
                *(_Float16*)(sKh + off) = h16;
                *(_Float16*)(sKl + off) = l16;
            } else {
                int d = c - 64, c8 = row >> 3, wi = row & 7;
                int off = d * 128 + (((c8 + d) & 7) << 4) + wi * 2;
                *(_Float16*)(sVh + off) = h16;
                *(_Float16*)(sVl + off) = l16;
            }
        }
    }
    __syncthreads();

    // ---- coalesced stores: 6 planes x 4 KB contiguous
    size_t pb = eb * (size_t)Tv * 32 + (size_t)tile * 2048;   // f16 elems
    _Float16* dsts[6] = {Qh + pb, Ql + pb, Kh + pb, Kl + pb, Vth + pb, Vtl + pb};
#pragma unroll
    for (int pl = 0; pl < 6; ++pl)
        ((float4*)dsts[pl])[tid] = ((const float4*)(qsm + pl * 4096))[tid];
}

// ---------------------------------------------------------------------------
// async global->LDS copy, 16 B/lane (global_load_lds_dwordx4); LDS dst =
// wave-uniform base + lane*16 (m97/m104 semantics).
// ---------------------------------------------------------------------------
__device__ __forceinline__ void load_lds16(const _Float16* g, char* l) {
    __builtin_amdgcn_global_load_lds(
        (const __attribute__((address_space(1))) void*)g,
        (__attribute__((address_space(3))) void*)l, 16, 0, 0);
}

// ---------------------------------------------------------------------------
// Kernel 3: MFMA flash attention + cosine epilogue (split-f16).
// DMA-staged double-buffered K/V planes (swizzle baked into global layout ->
// all ds_read_b128 <=2-way bank-aliased = free). ONE barrier per 64-key chunk.
// XCD-affinity: all 32 tiles of an (e,b) share bid&7 -> same XCD L2.
// LDS: dbuf 2 x (Kh 4K | Kl 4K | Vh 4K | Vl 4K) = 32 KB, P 4x2176 = 8704 B.
// ---------------------------------------------------------------------------
__global__ __launch_bounds__(256, 1) void attn_kernel(
    const _Float16* __restrict__ Qh, const _Float16* __restrict__ Ql,
    const _Float16* __restrict__ Kh, const _Float16* __restrict__ Kl,
    const _Float16* __restrict__ Vth, const _Float16* __restrict__ Vtl,
    const float* __restrict__ memv,
    float* __restrict__ out)
{
    __shared__ __align__(16) char smem[41472];
    const int PW = 32768;

    int bid  = blockIdx.x;              // 768
    // XCD-affinity decode: xcd = bid&7 -> eb in {xcd, xcd+8, xcd+16}
    int xcd  = bid & 7;
    int slot = bid >> 3;                // 0..95
    int tile = slot & 31;
    int ebi  = xcd + ((slot >> 5) << 3);  // 0..23
    int e    = ebi >> 3;
    int b    = ebi & 7;
    int tid  = threadIdx.x;
    int lane = tid & 63;
    int w    = tid >> 6;
    int quad = lane >> 4;
    int l15  = lane & 15;
    size_t eb = (size_t)ebi;
    int q0 = tile * 64 + w * 16;        // wave's 16 q-rows

    // Q B-frags (linear layout): lane reads Q[q0+l15][quad*8 .. +7]
    size_t qoff = (eb * Tv + (size_t)(q0 + l15)) * 32 + quad * 8;
    half8 qH = *(const half8*)(Qh + qoff);
    half8 qL = *(const half8*)(Ql + qoff);

    float4v O0 = {0.f, 0.f, 0.f, 0.f};  // O[q=quad*4+r][d=l15]
    float4v O1 = {0.f, 0.f, 0.f, 0.f};  // O[q=quad*4+r][d=16+l15]
    float m_run = -3.0e38f, l_run = 0.f;

    // wave w stages plane w: 0->Kh 1->Kl 2->Vth 3->Vtl (4 KB/chunk, 4 DMA)
    const _Float16* gplane = (w == 0) ? Kh : (w == 1) ? Kl : (w == 2) ? Vth : Vtl;
    gplane += eb * (size_t)Tv * 32;
    const _Float16* lanesrc = gplane + lane * 8;   // +16 B per lane

    // preload chunk 0 into buf 0
#pragma unroll
    for (int i = 0; i < 4; ++i)
        load_lds16(lanesrc + i * 512, smem + w * 4096 + i * 1024);

    for (int c = 0; c < 32; ++c) {
        int p = c & 1;
        __syncthreads();                 // own-wave vmcnt(0): chunk c resident;
                                         // all waves done reading buf p^1
        if (c + 1 < 32) {                // stage chunk c+1 into buf p^1 (async)
            const _Float16* src = lanesrc + (size_t)(c + 1) * 2048;
            char* dst = smem + (p ^ 1) * 16384 + w * 4096;
#pragma unroll
            for (int i = 0; i < 4; ++i)
                load_lds16(src + i * 512, dst + i * 1024);
        }
        const char* base = smem + p * 16384;

        // ---- S^T = K * Q^T : 4 key-subtiles x 3 split terms
        float s[16];
        float cmax = -3.0e38f;
#pragma unroll
        for (int tau = 0; tau < 4; ++tau) {
            int r = tau * 16 + l15;      // key row within chunk
            int sw = ((quad + r) & 3) << 4;
            half8 aH = *(const half8*)(base + r * 64 + sw);
            half8 aL = *(const half8*)(base + 4096 + r * 64 + sw);
            float4v acc = {0.f, 0.f, 0.f, 0.f};
            acc = __builtin_amdgcn_mfma_f32_16x16x32_f16(aH, qL, acc, 0, 0, 0);
            acc = __builtin_amdgcn_mfma_f32_16x16x32_f16(aL, qH, acc, 0, 0, 0);
            acc = __builtin_amdgcn_mfma_f32_16x16x32_f16(aH, qH, acc, 0, 0, 0);
#pragma unroll
            for (int r2 = 0; r2 < 4; ++r2) {
                s[tau * 4 + r2] = acc[r2];   // S^T[key=tau*16+quad*4+r2][q=l15]
                cmax = fmaxf(cmax, acc[r2]);
            }
        }
        cmax = fmaxf(cmax, __shfl_xor(cmax, 16));
        cmax = fmaxf(cmax, __shfl_xor(cmax, 32));
        float mNew  = fmaxf(m_run, cmax);
        float alpha = exp2f((m_run - mNew) * LOG2E);
        float psum = 0.f;
#pragma unroll
        for (int i = 0; i < 16; ++i) {
            s[i] = exp2f((s[i] - mNew) * LOG2E);
            psum += s[i];
        }
        psum += __shfl_xor(psum, 16);
        psum += __shfl_xor(psum, 32);
        l_run = l_run * alpha + psum;
        m_run = mNew;

#pragma unroll
        for (int r = 0; r < 4; ++r) {
            float ar = __shfl(alpha, quad * 4 + r, 16);
            O0[r] *= ar;
            O1[r] *= ar;
        }

        // ---- P (f16) -> per-wave LDS, rows q=l15 (136 B stride)
        char* pw = smem + PW + w * 2176 + l15 * 136;
#pragma unroll
        for (int tau = 0; tau < 4; ++tau) {
            fp16x2 h01 = __builtin_amdgcn_cvt_pkrtz(s[tau*4+0], s[tau*4+1]);
            fp16x2 h23 = __builtin_amdgcn_cvt_pkrtz(s[tau*4+2], s[tau*4+3]);
            uint2 u;
            u.x = __builtin_bit_cast(unsigned int, h01);
            u.y = __builtin_bit_cast(unsigned int, h23);
            *(uint2*)(pw + tau * 32 + quad * 8) = u;
        }
        __asm__ volatile("" ::: "memory");  // same-wave DS order: write < read

        // ---- O += P * V (V^T hi/lo from swizzled LDS)
#pragma unroll
        for (int ks = 0; ks < 2; ++ks) {
            int sw = ((ks * 4 + quad + l15) & 7) << 4;
            half8 pA  = *(const half8*)(pw + ks * 64 + quad * 16);
            half8 v0H = *(const half8*)(base + 8192  + l15 * 128 + sw);
            half8 v0L = *(const half8*)(base + 12288 + l15 * 128 + sw);
            half8 v1H = *(const half8*)(base + 8192  + (16 + l15) * 128 + sw);
            half8 v1L = *(const half8*)(base + 12288 + (16 + l15) * 128 + sw);
            O0 = __builtin_amdgcn_mfma_f32_16x16x32_f16(pA, v0H, O0, 0, 0, 0);
            O0 = __builtin_amdgcn_mfma_f32_16x16x32_f16(pA, v0L, O0, 0, 0, 0);
            O1 = __builtin_amdgcn_mfma_f32_16x16x32_f16(pA, v1H, O1, 0, 0, 0);
            O1 = __builtin_amdgcn_mfma_f32_16x16x32_f16(pA, v1L, O1, 0, 0, 0);
        }
    }

    // ---- epilogue: cosine(memories, O/l) per row (in-wave, shfl only)
    const float* mb = memv + (size_t)b * Tv * 32;
    float dotr[4], nor[4], nmr[4], lf[4];
#pragma unroll
    for (int r = 0; r < 4; ++r) {
        int trow = q0 + quad * 4 + r;
        float mv0 = mb[(size_t)trow * 32 + l15];
        float mv1 = mb[(size_t)trow * 32 + 16 + l15];
        float d  = O0[r] * mv0 + O1[r] * mv1;
        float n  = O0[r] * O0[r] + O1[r] * O1[r];
        float nm = mv0 * mv0 + mv1 * mv1;
#pragma unroll
        for (int delta = 1; delta < 16; delta <<= 1) {
            d  += __shfl_xor(d,  delta);
            n  += __shfl_xor(n,  delta);
            nm += __shfl_xor(nm, delta);
        }
        dotr[r] = d; nor[r] = n; nmr[r] = nm;
        lf[r] = __shfl(l_run, quad * 4 + r, 16);
    }
    if (l15 < 4) {
        int r = l15;
        float linv = 1.0f / lf[r];
        float na = fmaxf(sqrtf(nmr[r]), 1e-8f);
        float nb = fmaxf(sqrtf(nor[r]) * linv, 1e-8f);
        float cosv = (dotr[r] * linv) / (na * nb);
        int trow = q0 + quad * 4 + r;
        out[((size_t)b * Tv + trow) * Ev + e] = cosv;
    }
}

// ---------------------------------------------------------------------------
extern "C" void kernel_launch(void* const* d_in, const int* in_sizes, int n_in,
                              void* d_out, int out_size, void* d_ws, size_t ws_size,
                              hipStream_t stream) {
    const float* x      = (const float*)d_in[0];
    const float* hidden = (const float*)d_in[1];
    const float* memory = (const float*)d_in[2];
    const float* Wq     = (const float*)d_in[3];
    const float* Wk     = (const float*)d_in[4];
    const float* Wv     = (const float*)d_in[5];
    const float* iq     = (const float*)d_in[6];
    float* out          = (float*)d_out;           // [B,T,E] fp32

    char* ws = (char*)d_ws;
    // layout (bytes): memout f32 (2 MiB) | 6 f16 planes a 3 MiB = 20 MiB
    const size_t PLANE = (size_t)Ev * Bv * Tv * 32 * 2;   // 3,145,728 B
    float*    memout = (float*)ws;
    _Float16* Qh  = (_Float16*)(ws + 2097152);
    _Float16* Ql  = (_Float16*)(ws + 2097152 + PLANE);
    _Float16* Kh  = (_Float16*)(ws + 2097152 + 2 * PLANE);
    _Float16* Kl  = (_Float16*)(ws + 2097152 + 3 * PLANE);
    _Float16* Vth = (_Float16*)(ws + 2097152 + 4 * PLANE);
    _Float16* Vtl = (_Float16*)(ws + 2097152 + 5 * PLANE);

    mem_kernel<<<(Bv * Tv) / 256, 256, 0, stream>>>(x, memory, iq, memout);
    qkv_kernel<<<Ev * Bv * (Tv / 64), 256, 0, stream>>>(hidden, Wq, Wk, Wv,
                                                        Qh, Ql, Kh, Kl, Vth, Vtl);
    attn_kernel<<<Ev * Bv * (Tv / 64), 256, 0, stream>>>(Qh, Ql, Kh, Kl, Vth, Vtl,
                                                         memout, out);
}

// Round 8
// 157.693 us; speedup vs baseline: 7.2225x; 1.1457x over previous
//
#include <hip/hip_runtime.h>
#include <hip/hip_bf16.h>

// Problem sizes (fixed): B=8, T=2048, H=64, M=32, S=20, E=3, IN=32
#define Bv  8
#define Tv  2048
#define Hv  64
#define Mv  32
#define Sv  20
#define Ev  3
#define INv 32
#define LOG2E 1.44269504088896340736f

typedef __attribute__((ext_vector_type(8))) _Float16 half8;
typedef __attribute__((ext_vector_type(2))) __fp16 fp16x2;
typedef __attribute__((ext_vector_type(4))) float float4v;

// ---------------------------------------------------------------------------
// Kernel 1: memories[b,t,:] = softmax((x@IQ) @ mem^T) @ mem        [B*T, 32]
// ---------------------------------------------------------------------------
__global__ __launch_bounds__(256) void mem_kernel(
    const float* __restrict__ x,
    const float* __restrict__ memory,
    const float* __restrict__ iq,
    float* __restrict__ memout)
{
    __shared__ float sIQ[32][32];
    __shared__ float sM[20][32];
    int tid = threadIdx.x;
    for (int i = tid; i < 32 * 32; i += 256) sIQ[i >> 5][i & 31] = iq[i];
    for (int i = tid; i < 20 * 32; i += 256) sM[i >> 5][i & 31] = memory[i];
    __syncthreads();

    int t = blockIdx.x * 256 + tid;
    const float4* xr = (const float4*)(x + (size_t)t * INv);
    float xv[32];
#pragma unroll
    for (int i = 0; i < 8; ++i) {
        float4 v = xr[i];
        xv[4*i] = v.x; xv[4*i+1] = v.y; xv[4*i+2] = v.z; xv[4*i+3] = v.w;
    }
    float qm[32];
#pragma unroll
    for (int m = 0; m < 32; ++m) qm[m] = 0.f;
    for (int i = 0; i < 32; ++i) {
        float xi = xv[i];
#pragma unroll
        for (int m4 = 0; m4 < 8; ++m4) {
            float4 wv = *(const float4*)&sIQ[i][m4 * 4];
            qm[4*m4]   = fmaf(xi, wv.x, qm[4*m4]);
            qm[4*m4+1] = fmaf(xi, wv.y, qm[4*m4+1]);
            qm[4*m4+2] = fmaf(xi, wv.z, qm[4*m4+2]);
            qm[4*m4+3] = fmaf(xi, wv.w, qm[4*m4+3]);
        }
    }
    float sc[20];
#pragma unroll
    for (int j = 0; j < 20; ++j) {
        float acc = 0.f;
#pragma unroll
        for (int m = 0; m < 32; ++m) acc = fmaf(qm[m], sM[j][m], acc);
        sc[j] = acc;
    }
    float mx = sc[0];
#pragma unroll
    for (int j = 1; j < 20; ++j) mx = fmaxf(mx, sc[j]);
    float psum = 0.f, p[20];
#pragma unroll
    for (int j = 0; j < 20; ++j) { p[j] = exp2f((sc[j] - mx) * LOG2E); psum += p[j]; }
    float inv = 1.0f / psum;
    float mo[32];
#pragma unroll
    for (int m = 0; m < 32; ++m) mo[m] = 0.f;
    for (int j = 0; j < 20; ++j) {
        float pj = p[j];
#pragma unroll
        for (int m = 0; m < 32; ++m) mo[m] = fmaf(pj, sM[j][m], mo[m]);
    }
    float4* outp = (float4*)(memout + (size_t)t * Mv);
#pragma unroll
    for (int m4 = 0; m4 < 8; ++m4) {
        float4 v;
        v.x = mo[4*m4] * inv; v.y = mo[4*m4+1] * inv;
        v.z = mo[4*m4+2] * inv; v.w = mo[4*m4+3] * inv;
        outp[m4] = v;
    }
}

// ---------------------------------------------------------------------------
// Kernel 2: QKV -> 5 f16 planes (Vl dropped; Q pre-scaled by log2e).
// Layouts per eb, per 64-row tile (4 KB blocks):
//   Qh/Ql : linear [T][32]  (Q only feeds logits; scaled by LOG2E)
//   Kh/Kl : row r x 64 B, 16B-block q at ((q + r) & 3)
//   Vth   : row d (0..31) x 128 B (64 keys), 16B-block c8 at ((c8 + d) & 7)
// ---------------------------------------------------------------------------
__global__ __launch_bounds__(256) void qkv_kernel(
    const float* __restrict__ hidden,
    const float* __restrict__ Wq,
    const float* __restrict__ Wk,
    const float* __restrict__ Wv,
    _Float16* __restrict__ Qh, _Float16* __restrict__ Ql,
    _Float16* __restrict__ Kh, _Float16* __restrict__ Kl,
    _Float16* __restrict__ Vth)
{
    __shared__ __align__(16) char qsm[43008];
    float* sHT = (float*)qsm;                    // [h][t] stride 68
    float* sW  = (float*)(qsm + 17408);          // [h][96+pad] stride 100

    int bid  = blockIdx.x;              // 768 = E*B*32
    int tile = bid & 31;
    int b    = (bid >> 5) & 7;
    int e    = bid >> 8;
    int tid  = threadIdx.x;
    size_t eb = (size_t)(e * Bv + b);
    size_t row0 = eb * Tv + (size_t)tile * 64;
    const float* hbase = hidden + row0 * Hv;

    {
        int r  = tid >> 2;
        int c4 = tid & 3;
#pragma unroll
        for (int hh = 0; hh < 4; ++hh) {
            int h4 = c4 + hh * 4;
            float4 v = ((const float4*)(hbase + (size_t)r * Hv))[h4];
            sHT[(h4*4+0)*68 + r] = v.x; sHT[(h4*4+1)*68 + r] = v.y;
            sHT[(h4*4+2)*68 + r] = v.z; sHT[(h4*4+3)*68 + r] = v.w;
        }
    }
    {
        const float* wq = Wq + (size_t)e * Hv * Mv;
        const float* wk = Wk + (size_t)e * Hv * Mv;
        const float* wv = Wv + (size_t)e * Hv * Mv;
        for (int i = tid; i < Hv * Mv; i += 256) {
            int h = i >> 5, m = i & 31;
            sW[h*100 + m]      = wq[i];
            sW[h*100 + 32 + m] = wk[i];
            sW[h*100 + 64 + m] = wv[i];
        }
    }
    __syncthreads();

    int ty = tid >> 4, tx = tid & 15;
    float acc[4][6];
#pragma unroll
    for (int i = 0; i < 4; ++i)
#pragma unroll
        for (int j = 0; j < 6; ++j) acc[i][j] = 0.f;

    for (int h = 0; h < 64; ++h) {
        float4 av = *(const float4*)&sHT[h*68 + ty * 4];
        float a[4] = {av.x, av.y, av.z, av.w};
        float bb[6];
#pragma unroll
        for (int j = 0; j < 6; ++j) bb[j] = sW[h*100 + tx * 6 + j];
#pragma unroll
        for (int i = 0; i < 4; ++i)
#pragma unroll
            for (int j = 0; j < 6; ++j) acc[i][j] = fmaf(a[i], bb[j], acc[i][j]);
    }

    // ---- stage f16 hi/lo into LDS (5 planes x 4096 B)
    __syncthreads();
    char* sQh = qsm;
    char* sQl = qsm + 4096;
    char* sKh = qsm + 8192;
    char* sKl = qsm + 12288;
    char* sVh = qsm + 16384;
#pragma unroll
    for (int i = 0; i < 4; ++i) {
        int row = ty * 4 + i;
#pragma unroll
        for (int j = 0; j < 6; ++j) {
            int c = tx * 6 + j;
            float v = acc[i][j];
            if (c < 32) {
                v *= LOG2E;                       // logits in log2 domain
                _Float16 h16 = (_Float16)v;
                _Float16 l16 = (_Float16)(v - (float)h16);
                *(_Float16*)(sQh + row * 64 + c * 2) = h16;
                *(_Float16*)(sQl + row * 64 + c * 2) = l16;
            } else if (c < 64) {
                _Float16 h16 = (_Float16)v;
                _Float16 l16 = (_Float16)(v - (float)h16);
                int m = c - 32, q = m >> 3, wi = m & 7;
                int off = row * 64 + (((q + row) & 3) << 4) + wi * 2;
                *(_Float16*)(sKh + off) = h16;
                *(_Float16*)(sKl + off) = l16;
            } else {
                int d = c - 64, c8 = row >> 3, wi = row & 7;
                int off = d * 128 + (((c8 + d) & 7) << 4) + wi * 2;
                *(_Float16*)(sVh + off) = (_Float16)v;   // V: single f16
            }
        }
    }
    __syncthreads();

    // ---- coalesced stores: 5 planes x 4 KB contiguous
    size_t pb = eb * (size_t)Tv * 32 + (size_t)tile * 2048;   // f16 elems
    _Float16* dsts[5] = {Qh + pb, Ql + pb, Kh + pb, Kl + pb, Vth + pb};
#pragma unroll
    for (int pl = 0; pl < 5; ++pl)
        ((float4*)dsts[pl])[tid] = ((const float4*)(qsm + pl * 4096))[tid];
}

// ---------------------------------------------------------------------------
__device__ __forceinline__ void load_lds16(const _Float16* g, char* l) {
    __builtin_amdgcn_global_load_lds(
        (const __attribute__((address_space(1))) void*)g,
        (__attribute__((address_space(3))) void*)l, 16, 0, 0);
}

// ---------------------------------------------------------------------------
// Kernel 3: MFMA flash attention + cosine epilogue (split-f16 QK, f16 V).
// l_run DELETED: cosine is scale-invariant, O stays unnormalized.
// LDS: dbuf 2 x (Kh 4K | Kl 4K | Vh 4K) = 24576 + P 4x2048 (XOR-swizzled,
// conflict-minimal) = 32768 B. One barrier per 64-key chunk. 12 DMA/chunk
// split 3-per-wave. XCD-affinity block swizzle kept.
// ---------------------------------------------------------------------------
__global__ __launch_bounds__(256, 1) void attn_kernel(
    const _Float16* __restrict__ Qh, const _Float16* __restrict__ Ql,
    const _Float16* __restrict__ Kh, const _Float16* __restrict__ Kl,
    const _Float16* __restrict__ Vth,
    const float* __restrict__ memv,
    float* __restrict__ out)
{
    __shared__ __align__(16) char smem[32768];
    const int PW = 24576;

    int bid  = blockIdx.x;              // 768
    int xcd  = bid & 7;
    int slot = bid >> 3;                // 0..95
    int tile = slot & 31;
    int ebi  = xcd + ((slot >> 5) << 3);  // 0..23
    int e    = ebi >> 3;
    int b    = ebi & 7;
    int tid  = threadIdx.x;
    int lane = tid & 63;
    int w    = tid >> 6;
    int quad = lane >> 4;
    int l15  = lane & 15;
    size_t eb = (size_t)ebi;
    int q0 = tile * 64 + w * 16;

    // Q B-frags (pre-scaled by log2e in qkv)
    size_t qoff = (eb * Tv + (size_t)(q0 + l15)) * 32 + quad * 8;
    half8 qH = *(const half8*)(Qh + qoff);
    half8 qL = *(const half8*)(Ql + qoff);

    float4v O0 = {0.f, 0.f, 0.f, 0.f};  // O[q=quad*4+r][d=l15]
    float4v O1 = {0.f, 0.f, 0.f, 0.f};  // O[q=quad*4+r][d=16+l15]
    float m_run = -3.0e38f;

    // 12 x 1KB DMA per chunk, 3 per wave: idx = w*3+j -> plane idx>>2, part idx&3
    size_t ebOff = eb * (size_t)Tv * 32;
    const _Float16* gp[3] = {Kh + ebOff, Kl + ebOff, Vth + ebOff};

    // preload chunk 0 into buf 0
#pragma unroll
    for (int j = 0; j < 3; ++j) {
        int idx = w * 3 + j, p = idx >> 2, k = idx & 3;
        load_lds16(gp[p] + (size_t)k * 512 + lane * 8,
                   smem + p * 4096 + k * 1024);
    }

    for (int c = 0; c < 32; ++c) {
        int pb = c & 1;
        __syncthreads();                 // chunk c resident; buf pb^1 free
        if (c + 1 < 32) {
#pragma unroll
            for (int j = 0; j < 3; ++j) {
                int idx = w * 3 + j, p = idx >> 2, k = idx & 3;
                load_lds16(gp[p] + (size_t)(c + 1) * 2048 + k * 512 + lane * 8,
                           smem + (pb ^ 1) * 12288 + p * 4096 + k * 1024);
            }
        }
        const char* base = smem + pb * 12288;

        // ---- S^T = K * Q^T : 4 key-subtiles x 3 split terms (log2 domain)
        float s[16];
        float cmax = -3.0e38f;
#pragma unroll
        for (int tau = 0; tau < 4; ++tau) {
            int r = tau * 16 + l15;
            int sw = ((quad + r) & 3) << 4;
            half8 aH = *(const half8*)(base + r * 64 + sw);
            half8 aL = *(const half8*)(base + 4096 + r * 64 + sw);
            float4v acc = {0.f, 0.f, 0.f, 0.f};
            acc = __builtin_amdgcn_mfma_f32_16x16x32_f16(aH, qL, acc, 0, 0, 0);
            acc = __builtin_amdgcn_mfma_f32_16x16x32_f16(aL, qH, acc, 0, 0, 0);
            acc = __builtin_amdgcn_mfma_f32_16x16x32_f16(aH, qH, acc, 0, 0, 0);
#pragma unroll
            for (int r2 = 0; r2 < 4; ++r2) {
                s[tau * 4 + r2] = acc[r2];
                cmax = fmaxf(cmax, acc[r2]);
            }
        }
        cmax = fmaxf(cmax, __shfl_xor(cmax, 16));
        cmax = fmaxf(cmax, __shfl_xor(cmax, 32));
        float mNew  = fmaxf(m_run, cmax);
        float alpha = exp2f(m_run - mNew);
#pragma unroll
        for (int i = 0; i < 16; ++i)
            s[i] = exp2f(s[i] - mNew);
        m_run = mNew;

#pragma unroll
        for (int r = 0; r < 4; ++r) {
            float ar = __shfl(alpha, quad * 4 + r, 16);
            O0[r] *= ar;
            O1[r] *= ar;
        }

        // ---- P (f16) -> per-wave LDS, 128-B rows, 16B-block XOR swizzle
        char* pw = smem + PW + w * 2048 + l15 * 128;
        int xr = l15 & 7;
#pragma unroll
        for (int tau = 0; tau < 4; ++tau) {
            fp16x2 h01 = __builtin_amdgcn_cvt_pkrtz(s[tau*4+0], s[tau*4+1]);
            fp16x2 h23 = __builtin_amdgcn_cvt_pkrtz(s[tau*4+2], s[tau*4+3]);
            uint2 u;
            u.x = __builtin_bit_cast(unsigned int, h01);
            u.y = __builtin_bit_cast(unsigned int, h23);
            int bi = tau * 2 + (quad >> 1);          // 16-B block index
            *(uint2*)(pw + ((bi ^ xr) << 4) + (quad & 1) * 8) = u;
        }
        __asm__ volatile("" ::: "memory");

        // ---- O += P * V (f16 V from swizzled LDS)
#pragma unroll
        for (int ks = 0; ks < 2; ++ks) {
            int swv = ((ks * 4 + quad + l15) & 7) << 4;
            half8 pA  = *(const half8*)(pw + (((ks * 4 + quad) ^ xr) << 4));
            half8 v0H = *(const half8*)(base + 8192 + l15 * 128 + swv);
            half8 v1H = *(const half8*)(base + 8192 + (16 + l15) * 128 + swv);
            O0 = __builtin_amdgcn_mfma_f32_16x16x32_f16(pA, v0H, O0, 0, 0, 0);
            O1 = __builtin_amdgcn_mfma_f32_16x16x32_f16(pA, v1H, O1, 0, 0, 0);
        }
    }

    // ---- epilogue: cosine(memories, O) — scale-invariant, no L needed
    const float* mb = memv + (size_t)b * Tv * 32;
    float dotr[4], nor[4], nmr[4];
#pragma unroll
    for (int r = 0; r < 4; ++r) {
        int trow = q0 + quad * 4 + r;
        float mv0 = mb[(size_t)trow * 32 + l15];
        float mv1 = mb[(size_t)trow * 32 + 16 + l15];
        float d  = O0[r] * mv0 + O1[r] * mv1;
        float n  = O0[r] * O0[r] + O1[r] * O1[r];
        float nm = mv0 * mv0 + mv1 * mv1;
#pragma unroll
        for (int delta = 1; delta < 16; delta <<= 1) {
            d  += __shfl_xor(d,  delta);
            n  += __shfl_xor(n,  delta);
            nm += __shfl_xor(nm, delta);
        }
        dotr[r] = d; nor[r] = n; nmr[r] = nm;
    }
    if (l15 < 4) {
        int r = l15;
        float na = fmaxf(sqrtf(nmr[r]), 1e-8f);
        float nb = fmaxf(sqrtf(nor[r]), 1e-30f);
        float cosv = dotr[r] / (na * nb);
        int trow = q0 + quad * 4 + r;
        out[((size_t)b * Tv + trow) * Ev + e] = cosv;
    }
}

// ---------------------------------------------------------------------------
extern "C" void kernel_launch(void* const* d_in, const int* in_sizes, int n_in,
                              void* d_out, int out_size, void* d_ws, size_t ws_size,
                              hipStream_t stream) {
    const float* x      = (const float*)d_in[0];
    const float* hidden = (const float*)d_in[1];
    const float* memory = (const float*)d_in[2];
    const float* Wq     = (const float*)d_in[3];
    const float* Wk     = (const float*)d_in[4];
    const float* Wv     = (const float*)d_in[5];
    const float* iq     = (const float*)d_in[6];
    float* out          = (float*)d_out;           // [B,T,E] fp32

    char* ws = (char*)d_ws;
    // layout (bytes): memout f32 (2 MiB) | 5 f16 planes a 3 MiB = 17 MiB
    const size_t PLANE = (size_t)Ev * Bv * Tv * 32 * 2;   // 3,145,728 B
    float*    memout = (float*)ws;
    _Float16* Qh  = (_Float16*)(ws + 2097152);
    _Float16* Ql  = (_Float16*)(ws + 2097152 + PLANE);
    _Float16* Kh  = (_Float16*)(ws + 2097152 + 2 * PLANE);
    _Float16* Kl  = (_Float16*)(ws + 2097152 + 3 * PLANE);
    _Float16* Vth = (_Float16*)(ws + 2097152 + 4 * PLANE);

    mem_kernel<<<(Bv * Tv) / 256, 256, 0, stream>>>(x, memory, iq, memout);
    qkv_kernel<<<Ev * Bv * (Tv / 64), 256, 0, stream>>>(hidden, Wq, Wk, Wv,
                                                        Qh, Ql, Kh, Kl, Vth);
    attn_kernel<<<Ev * Bv * (Tv / 64), 256, 0, stream>>>(Qh, Ql, Kh, Kl, Vth,
                                                         memout, out);
}